// Round 1
// baseline (2164.936 us; speedup 1.0000x reference)
//
#include <hip/hip_runtime.h>
#include <math.h>

constexpr int B = 2, C = 64, H = 80, W = 80, HW = H * W, COUT = 64;

// ---------------------------------------------------------------------------
// Transpose x: NCHW -> NHWC (channel-contiguous) via LDS tiles.
// ---------------------------------------------------------------------------
__global__ __launch_bounds__(256) void transpose_nchw_nhwc(
    const float* __restrict__ x, float* __restrict__ xh) {
  __shared__ float tile[64][65];
  int blk = blockIdx.x;                 // B * (HW/64) blocks
  int b = blk / (HW / 64);
  int p0 = (blk % (HW / 64)) * 64;
  int lane = threadIdx.x & 63, row = threadIdx.x >> 6;
#pragma unroll
  for (int it = 0; it < 16; ++it) {
    int ci = it * 4 + row;
    tile[ci][lane] = x[(size_t)(b * C + ci) * HW + p0 + lane];
  }
  __syncthreads();
#pragma unroll
  for (int it = 0; it < 16; ++it) {
    int pl = it * 4 + row;
    xh[((size_t)b * HW + p0 + pl) * C + lane] = tile[lane][pl];
  }
}

// ---------------------------------------------------------------------------
// Weight prep per branch:
//  wcomb[(kxy*C+ci)*C3 + co]  (co<2KK from w_off, else w_mask)
//  bcomb[co]
//  wd[(t*C+ci)*COUT + co] = w_dcn[co][ci][t]
// ---------------------------------------------------------------------------
template <int K>
__global__ __launch_bounds__(256) void prep_weights(
    const float* __restrict__ w_off, const float* __restrict__ b_off,
    const float* __restrict__ w_mask, const float* __restrict__ b_mask,
    const float* __restrict__ w_dcn, float* __restrict__ wcomb,
    float* __restrict__ bcomb, float* __restrict__ wd) {
  constexpr int KK = K * K, C3 = 3 * KK;
  const int n1 = KK * C * C3;
  const int n2 = C3;
  const int n3 = KK * C * COUT;
  const int total = n1 + n2 + n3;
  for (int i = blockIdx.x * blockDim.x + threadIdx.x; i < total;
       i += gridDim.x * blockDim.x) {
    if (i < n1) {
      int co = i % C3;
      int rest = i / C3;
      int ci = rest % C;
      int kxy = rest / C;
      float v = (co < 2 * KK) ? w_off[(co * C + ci) * KK + kxy]
                              : w_mask[((co - 2 * KK) * C + ci) * KK + kxy];
      wcomb[i] = v;
    } else if (i < n1 + n2) {
      int co = i - n1;
      bcomb[co] = (co < 2 * KK) ? b_off[co] : b_mask[co - 2 * KK];
    } else {
      int j = i - n1 - n2;
      int co = j % COUT;
      int rest = j / COUT;
      int ci = rest % C;
      int t = rest / C;
      wd[j] = w_dcn[(co * C + ci) * KK + t];
    }
  }
}

// ---------------------------------------------------------------------------
// Fused offset+mask conv. 4-pixel register blocking along x.
// Epilogue: offset channels get the base grid added (stores py/px directly),
// mask channels get sigmoid. Output layout: convout[pix*C3 + co].
// ---------------------------------------------------------------------------
template <int K, int C3>
__global__ __launch_bounds__(256) void conv_offmask_kernel(
    const float* __restrict__ xh, const float* __restrict__ wcomb,
    const float* __restrict__ bcomb, float* __restrict__ convout) {
  constexpr int PAD = K / 2;
  constexpr int KK = K * K;
  const int N = B * H * (W / 4) * C3;
  for (int i = blockIdx.x * blockDim.x + threadIdx.x; i < N;
       i += gridDim.x * blockDim.x) {
    int co = i % C3;
    int pg = i / C3;
    int xg = pg % (W / 4);
    int by = pg / (W / 4);
    int y = by % H;
    int b = by / H;
    int x0 = xg * 4;
    float bias = bcomb[co];
    float acc0 = bias, acc1 = bias, acc2 = bias, acc3 = bias;
    for (int ky = 0; ky < K; ++ky) {
      int yy = y + ky - PAD;
      if ((unsigned)yy >= (unsigned)H) continue;
      const float* xrow = xh + (size_t)((b * H + yy) * W) * C;
      for (int kx = 0; kx < K; ++kx) {
        int xx = x0 + kx - PAD;
        const float* wp = wcomb + (size_t)((ky * K + kx) * C) * C3 + co;
        if (xx >= 0 && xx + 3 < W) {
          const float4* xp0 = reinterpret_cast<const float4*>(xrow + (xx + 0) * C);
          const float4* xp1 = reinterpret_cast<const float4*>(xrow + (xx + 1) * C);
          const float4* xp2 = reinterpret_cast<const float4*>(xrow + (xx + 2) * C);
          const float4* xp3 = reinterpret_cast<const float4*>(xrow + (xx + 3) * C);
#pragma unroll 4
          for (int c4 = 0; c4 < C / 4; ++c4) {
            float w0 = wp[(4 * c4 + 0) * C3];
            float w1 = wp[(4 * c4 + 1) * C3];
            float w2 = wp[(4 * c4 + 2) * C3];
            float w3 = wp[(4 * c4 + 3) * C3];
            float4 a0 = xp0[c4], a1 = xp1[c4], a2 = xp2[c4], a3 = xp3[c4];
            acc0 += a0.x * w0 + a0.y * w1 + a0.z * w2 + a0.w * w3;
            acc1 += a1.x * w0 + a1.y * w1 + a1.z * w2 + a1.w * w3;
            acc2 += a2.x * w0 + a2.y * w1 + a2.z * w2 + a2.w * w3;
            acc3 += a3.x * w0 + a3.y * w1 + a3.z * w2 + a3.w * w3;
          }
        } else {
          int xa = min(max(xx + 0, 0), W - 1);
          int xb = min(max(xx + 1, 0), W - 1);
          int xc = min(max(xx + 2, 0), W - 1);
          int xd = min(max(xx + 3, 0), W - 1);
          float f0 = ((unsigned)(xx + 0) < (unsigned)W) ? 1.f : 0.f;
          float f1 = ((unsigned)(xx + 1) < (unsigned)W) ? 1.f : 0.f;
          float f2 = ((unsigned)(xx + 2) < (unsigned)W) ? 1.f : 0.f;
          float f3 = ((unsigned)(xx + 3) < (unsigned)W) ? 1.f : 0.f;
          const float4* xp0 = reinterpret_cast<const float4*>(xrow + xa * C);
          const float4* xp1 = reinterpret_cast<const float4*>(xrow + xb * C);
          const float4* xp2 = reinterpret_cast<const float4*>(xrow + xc * C);
          const float4* xp3 = reinterpret_cast<const float4*>(xrow + xd * C);
#pragma unroll 4
          for (int c4 = 0; c4 < C / 4; ++c4) {
            float w0 = wp[(4 * c4 + 0) * C3];
            float w1 = wp[(4 * c4 + 1) * C3];
            float w2 = wp[(4 * c4 + 2) * C3];
            float w3 = wp[(4 * c4 + 3) * C3];
            float4 a0 = xp0[c4], a1 = xp1[c4], a2 = xp2[c4], a3 = xp3[c4];
            acc0 += f0 * (a0.x * w0 + a0.y * w1 + a0.z * w2 + a0.w * w3);
            acc1 += f1 * (a1.x * w0 + a1.y * w1 + a1.z * w2 + a1.w * w3);
            acc2 += f2 * (a2.x * w0 + a2.y * w1 + a2.z * w2 + a2.w * w3);
            acc3 += f3 * (a3.x * w0 + a3.y * w1 + a3.z * w2 + a3.w * w3);
          }
        }
      }
    }
    // Epilogue: add base grid to offsets (=> stores py/px), sigmoid masks.
    int pixbase = (b * H + y) * W + x0;
    float accs[4] = {acc0, acc1, acc2, acc3};
#pragma unroll
    for (int j = 0; j < 4; ++j) {
      float v = accs[j];
      if (co < 2 * KK) {
        int t = co >> 1;
        if ((co & 1) == 0)
          v += (float)(y - PAD + t / K);  // py = base_y + oy
        else
          v += (float)(x0 + j - PAD + t % K);  // px = base_x + ox
      } else {
        v = 1.f / (1.f + expf(-v));  // sigmoid(mask)
      }
      convout[(size_t)(pixbase + j) * C3 + co] = v;
    }
  }
}

// ---------------------------------------------------------------------------
// Deformable sampling + einsum. One block (256 thr) per output pixel.
// 4 taps staged per round into LDS (bilinear, channel-contiguous gathers),
// then 64x64 matvec per tap. Final reduction across the 4 tap-quarters.
// ---------------------------------------------------------------------------
template <int K>
__global__ __launch_bounds__(256) void dcn_sample_gemm_kernel(
    const float* __restrict__ xh, const float* __restrict__ convout,
    const float* __restrict__ wd, float* __restrict__ out, int br_off) {
  constexpr int KK = K * K, C3 = 3 * KK;
  constexpr int ROUNDS = (KK + 3) / 4;
  __shared__ float s_pym[C3];
  __shared__ float s_samp[4][C];
  __shared__ float s_part[256];
  int pix = blockIdx.x;  // 0 .. B*HW-1
  int x = pix % W;
  int y = (pix / W) % H;
  int b = pix / HW;
  int tid = threadIdx.x;
  int lane = tid & 63;
  int q = tid >> 6;
  if (tid < C3) s_pym[tid] = convout[(size_t)pix * C3 + tid];
  __syncthreads();
  const float* xb = xh + (size_t)b * HW * C;
  float acc = 0.f;
  for (int r = 0; r < ROUNDS; ++r) {
    int t = r * 4 + q;
    if (t < KK) {
      float py = s_pym[2 * t], px = s_pym[2 * t + 1], m = s_pym[2 * KK + t];
      float fy = floorf(py), fx = floorf(px);
      float wy1 = py - fy, wx1 = px - fx;
      float wy0 = 1.f - wy1, wx0 = 1.f - wx1;
      int y0 = (int)fy, x0 = (int)fx;
      int y1 = y0 + 1, x1 = x0 + 1;
      bool vy0 = (y0 >= 0) & (y0 < H), vy1 = (y1 >= 0) & (y1 < H);
      bool vx0 = (x0 >= 0) & (x0 < W), vx1 = (x1 >= 0) & (x1 < W);
      float c00 = wy0 * wx0 * ((vy0 & vx0) ? 1.f : 0.f);
      float c01 = wy0 * wx1 * ((vy0 & vx1) ? 1.f : 0.f);
      float c10 = wy1 * wx0 * ((vy1 & vx0) ? 1.f : 0.f);
      float c11 = wy1 * wx1 * ((vy1 & vx1) ? 1.f : 0.f);
      int y0c = min(max(y0, 0), H - 1), y1c = min(max(y1, 0), H - 1);
      int x0c = min(max(x0, 0), W - 1), x1c = min(max(x1, 0), W - 1);
      float v00 = xb[(size_t)(y0c * W + x0c) * C + lane];
      float v01 = xb[(size_t)(y0c * W + x1c) * C + lane];
      float v10 = xb[(size_t)(y1c * W + x0c) * C + lane];
      float v11 = xb[(size_t)(y1c * W + x1c) * C + lane];
      s_samp[q][lane] = m * (c00 * v00 + c01 * v01 + c10 * v10 + c11 * v11);
    }
    __syncthreads();
    if (t < KK) {
      const float* wp = wd + (size_t)(t * C) * COUT + lane;  // lane == co
      const float4* sp = reinterpret_cast<const float4*>(s_samp[q]);
#pragma unroll
      for (int c4 = 0; c4 < C / 4; ++c4) {
        float4 s = sp[c4];
        acc += s.x * wp[(4 * c4 + 0) * COUT] + s.y * wp[(4 * c4 + 1) * COUT] +
               s.z * wp[(4 * c4 + 2) * COUT] + s.w * wp[(4 * c4 + 3) * COUT];
      }
    }
    __syncthreads();
  }
  s_part[tid] = acc;
  __syncthreads();
  if (tid < 64) {
    float v = s_part[tid] + s_part[tid + 64] + s_part[tid + 128] + s_part[tid + 192];
    out[((size_t)(b * (3 * COUT) + br_off + tid)) * HW + y * W + x] = v;
  }
}

// ---------------------------------------------------------------------------
// Launch
// ---------------------------------------------------------------------------
extern "C" void kernel_launch(void* const* d_in, const int* in_sizes, int n_in,
                              void* d_out, int out_size, void* d_ws,
                              size_t ws_size, hipStream_t stream) {
  const float* x = (const float*)d_in[0];
  const float* w_off3 = (const float*)d_in[1];
  const float* b_off3 = (const float*)d_in[2];
  const float* w_mask3 = (const float*)d_in[3];
  const float* b_mask3 = (const float*)d_in[4];
  const float* w_dcn3 = (const float*)d_in[5];
  const float* w_off5 = (const float*)d_in[6];
  const float* b_off5 = (const float*)d_in[7];
  const float* w_mask5 = (const float*)d_in[8];
  const float* b_mask5 = (const float*)d_in[9];
  const float* w_dcn5 = (const float*)d_in[10];
  const float* w_off7 = (const float*)d_in[11];
  const float* b_off7 = (const float*)d_in[12];
  const float* w_mask7 = (const float*)d_in[13];
  const float* b_mask7 = (const float*)d_in[14];
  const float* w_dcn7 = (const float*)d_in[15];
  float* out = (float*)d_out;
  float* ws = (float*)d_ws;

  // Workspace layout (floats, all 16B aligned)
  size_t off = 0;
  auto alloc = [&](size_t n) {
    size_t p = off;
    off += (n + 3) & ~(size_t)3;
    return ws + p;
  };
  float* xh = alloc((size_t)B * HW * C);        // 819200
  float* co3 = alloc((size_t)B * HW * 27);      // 345600
  float* co5 = alloc((size_t)B * HW * 75);      // 960000
  float* co7 = alloc((size_t)B * HW * 147);     // 1881600
  float* wc3 = alloc(9 * C * 27);
  float* bc3 = alloc(27);
  float* wc5 = alloc(25 * C * 75);
  float* bc5 = alloc(75);
  float* wc7 = alloc(49 * C * 147);
  float* bc7 = alloc(147);
  float* wd3 = alloc(9 * C * COUT);
  float* wd5 = alloc(25 * C * COUT);
  float* wd7 = alloc(49 * C * COUT);

  // 1) x -> NHWC
  transpose_nchw_nhwc<<<B * (HW / 64), 256, 0, stream>>>(x, xh);

  // 2) weight prep
  prep_weights<3><<<128, 256, 0, stream>>>(w_off3, b_off3, w_mask3, b_mask3,
                                           w_dcn3, wc3, bc3, wd3);
  prep_weights<5><<<256, 256, 0, stream>>>(w_off5, b_off5, w_mask5, b_mask5,
                                           w_dcn5, wc5, bc5, wd5);
  prep_weights<7><<<512, 256, 0, stream>>>(w_off7, b_off7, w_mask7, b_mask7,
                                           w_dcn7, wc7, bc7, wd7);

  // 3) offset+mask convs (stores py/px and sigmoided mask)
  {
    int n3 = B * H * (W / 4) * 27;
    int n5 = B * H * (W / 4) * 75;
    int n7 = B * H * (W / 4) * 147;
    conv_offmask_kernel<3, 27><<<(n3 + 255) / 256, 256, 0, stream>>>(xh, wc3, bc3, co3);
    conv_offmask_kernel<5, 75><<<(n5 + 255) / 256, 256, 0, stream>>>(xh, wc5, bc5, co5);
    conv_offmask_kernel<7, 147><<<(n7 + 255) / 256, 256, 0, stream>>>(xh, wc7, bc7, co7);
  }

  // 4) deformable sampling + einsum
  dcn_sample_gemm_kernel<3><<<B * HW, 256, 0, stream>>>(xh, co3, wd3, out, 0);
  dcn_sample_gemm_kernel<5><<<B * HW, 256, 0, stream>>>(xh, co5, wd5, out, 64);
  dcn_sample_gemm_kernel<7><<<B * HW, 256, 0, stream>>>(xh, co7, wd7, out, 128);
}

// Round 2
// 875.395 us; speedup vs baseline: 2.4731x; 2.4731x over previous
//
#include <hip/hip_runtime.h>
#include <math.h>

constexpr int B = 2, C = 64, H = 80, W = 80, HW = H * W, COUT = 64;

typedef __attribute__((ext_vector_type(8))) short short8;   // 8 bf16
typedef __attribute__((ext_vector_type(4))) float f32x4;

__device__ inline ushort f2bf(float f) {
  unsigned u = __float_as_uint(f);
  unsigned r = u + 0x7fff + ((u >> 16) & 1);   // RNE
  return (ushort)(r >> 16);
}

// ---------------------------------------------------------------------------
// Transpose x: NCHW fp32 -> NHWC fp32 (for sampler) + NHWC bf16 (for MFMA).
// ---------------------------------------------------------------------------
__global__ __launch_bounds__(256) void transpose_nchw_nhwc(
    const float* __restrict__ x, float* __restrict__ xh,
    ushort* __restrict__ xhb) {
  __shared__ float tile[64][65];
  int blk = blockIdx.x;                 // B * (HW/64) blocks
  int b = blk / (HW / 64);
  int p0 = (blk % (HW / 64)) * 64;
  int lane = threadIdx.x & 63, row = threadIdx.x >> 6;
#pragma unroll
  for (int it = 0; it < 16; ++it) {
    int ci = it * 4 + row;
    tile[ci][lane] = x[(size_t)(b * C + ci) * HW + p0 + lane];
  }
  __syncthreads();
#pragma unroll
  for (int it = 0; it < 16; ++it) {
    int pl = it * 4 + row;
    float v = tile[lane][pl];
    size_t o = ((size_t)b * HW + p0 + pl) * C + lane;
    xh[o] = v;
    xhb[o] = f2bf(v);
  }
}

// ---------------------------------------------------------------------------
// Weight prep per branch:
//  wtb[n*KDIM + t*C+ci] = bf16 of (n<2KK ? w_off[n][ci][t] : n<C3 ? w_mask : 0)
//  bcomb[co] fp32 combined bias
//  wd[(t*C+ci)*COUT + co] = w_dcn[co][ci][t]  (fp32, sampler layout)
// ---------------------------------------------------------------------------
template <int K, int NP>
__global__ __launch_bounds__(256) void prep_weights(
    const float* __restrict__ w_off, const float* __restrict__ b_off,
    const float* __restrict__ w_mask, const float* __restrict__ b_mask,
    const float* __restrict__ w_dcn, ushort* __restrict__ wtb,
    float* __restrict__ bcomb, float* __restrict__ wd) {
  constexpr int KK = K * K, C3 = 3 * KK, KDIM = KK * C;
  const int n1 = NP * KDIM;
  const int n2 = C3;
  const int n3 = KK * C * COUT;
  const int total = n1 + n2 + n3;
  for (int i = blockIdx.x * blockDim.x + threadIdx.x; i < total;
       i += gridDim.x * blockDim.x) {
    if (i < n1) {
      int co = i / KDIM;
      int k = i % KDIM;
      int t = k / C;
      int ci = k % C;
      float v = 0.f;
      if (co < 2 * KK) v = w_off[(co * C + ci) * KK + t];
      else if (co < C3) v = w_mask[((co - 2 * KK) * C + ci) * KK + t];
      wtb[i] = f2bf(v);
    } else if (i < n1 + n2) {
      int co = i - n1;
      bcomb[co] = (co < 2 * KK) ? b_off[co] : b_mask[co - 2 * KK];
    } else {
      int j = i - n1 - n2;
      int co = j % COUT;
      int rest = j / COUT;
      int ci = rest % C;
      int t = rest / C;
      wd[j] = w_dcn[(co * C + ci) * KK + t];
    }
  }
}

// ---------------------------------------------------------------------------
// Implicit-im2col bf16 MFMA GEMM for the offset+mask conv.
//   A[m][k] = xhb[b, y+ky-PAD, x+kx-PAD, ci]   (k = (ky*K+kx)*C + ci, zero pad)
//   Bmat[k][n] = wtb[n][k]
// Each wave: one 16-pixel m-tile x one n-group (half of NT n-tiles).
// Epilogue: bias + base-grid add (offsets) / sigmoid (masks) -> convout[pix][C3]
// ---------------------------------------------------------------------------
template <int K, int NT>
__global__ __launch_bounds__(256) void conv_gemm(
    const ushort* __restrict__ xhb, const ushort* __restrict__ wtb,
    const float* __restrict__ bcomb, float* __restrict__ convout) {
  constexpr int PAD = K / 2, KK = K * K, C3 = 3 * KK, KDIM = KK * C;
  constexpr int NTA = (NT + 1) / 2;
  int tid = threadIdx.x;
  int wid = blockIdx.x * 4 + (tid >> 6);   // global wave id
  int mt = wid >> 1;                       // m-tile (16 pixels)
  int g = wid & 1;                         // n-group
  int j0 = g * NTA;
  int jn = min(NT - j0, NTA);
  int l = tid & 63;
  int lm = l & 15, lk = l >> 4;            // lk in 0..3
  int m0 = mt * 16;
  int b = m0 / HW;
  int rem = m0 % HW;
  int y = rem / W;
  int x0 = rem % W;                        // 16 | m0, 16 | W=80 -> same row
  const ushort* xbase = xhb + (size_t)b * HW * C;
  f32x4 acc[NTA];
#pragma unroll
  for (int j = 0; j < NTA; ++j) acc[j] = f32x4{0.f, 0.f, 0.f, 0.f};

  for (int t = 0; t < KK; ++t) {
    int yy = y + t / K - PAD;
    if ((unsigned)yy >= (unsigned)H) continue;   // wave-uniform
    int xx = x0 + lm + (t % K) - PAD;
    bool vx = (unsigned)xx < (unsigned)W;
    const ushort* aptr = xbase + ((size_t)(yy * W + (vx ? xx : 0))) * C + lk * 8;
    const ushort* wptr = wtb + (size_t)t * C + lk * 8;
#pragma unroll
    for (int half = 0; half < 2; ++half) {
      short8 a = {0, 0, 0, 0, 0, 0, 0, 0};
      if (vx) a = *(const short8*)(aptr + half * 32);
#pragma unroll
      for (int jj = 0; jj < NTA; ++jj) {
        if (jj < jn) {
          int n = (j0 + jj) * 16 + lm;
          short8 bf = *(const short8*)(wptr + half * 32 + (size_t)n * KDIM);
          acc[jj] = __builtin_amdgcn_mfma_f32_16x16x32_bf16(a, bf, acc[jj], 0, 0, 0);
        }
      }
    }
  }

  // Epilogue. D mapping: col(n)=l&15, row(m)=lk*4+r.
#pragma unroll
  for (int jj = 0; jj < NTA; ++jj) {
    if (jj >= jn) continue;
    int co = (j0 + jj) * 16 + lm;
    if (co >= C3) continue;
    float bs = bcomb[co];
    bool isoff = co < 2 * KK;
    int tp = co >> 1;
#pragma unroll
    for (int r = 0; r < 4; ++r) {
      int xr = x0 + lk * 4 + r;
      int pix = m0 + lk * 4 + r;           // = b*HW + y*W + xr
      float v = acc[jj][r] + bs;
      if (isoff) {
        v += (co & 1) ? (float)(xr - PAD + tp % K)    // px
                      : (float)(y - PAD + tp / K);    // py
      } else {
        v = 1.f / (1.f + expf(-v));
      }
      convout[(size_t)pix * C3 + co] = v;
    }
  }
}

// ---------------------------------------------------------------------------
// Deformable sampling + einsum (fp32, unchanged this round).
// ---------------------------------------------------------------------------
template <int K>
__global__ __launch_bounds__(256) void dcn_sample_gemm_kernel(
    const float* __restrict__ xh, const float* __restrict__ convout,
    const float* __restrict__ wd, float* __restrict__ out, int br_off) {
  constexpr int KK = K * K, C3 = 3 * KK;
  constexpr int ROUNDS = (KK + 3) / 4;
  __shared__ float s_pym[C3];
  __shared__ float s_samp[4][C];
  __shared__ float s_part[256];
  int pix = blockIdx.x;  // 0 .. B*HW-1
  int x = pix % W;
  int y = (pix / W) % H;
  int b = pix / HW;
  int tid = threadIdx.x;
  int lane = tid & 63;
  int q = tid >> 6;
  if (tid < C3) s_pym[tid] = convout[(size_t)pix * C3 + tid];
  __syncthreads();
  const float* xb = xh + (size_t)b * HW * C;
  float acc = 0.f;
  for (int r = 0; r < ROUNDS; ++r) {
    int t = r * 4 + q;
    if (t < KK) {
      float py = s_pym[2 * t], px = s_pym[2 * t + 1], m = s_pym[2 * KK + t];
      float fy = floorf(py), fx = floorf(px);
      float wy1 = py - fy, wx1 = px - fx;
      float wy0 = 1.f - wy1, wx0 = 1.f - wx1;
      int y0 = (int)fy, x0 = (int)fx;
      int y1 = y0 + 1, x1 = x0 + 1;
      bool vy0 = (y0 >= 0) & (y0 < H), vy1 = (y1 >= 0) & (y1 < H);
      bool vx0 = (x0 >= 0) & (x0 < W), vx1 = (x1 >= 0) & (x1 < W);
      float c00 = wy0 * wx0 * ((vy0 & vx0) ? 1.f : 0.f);
      float c01 = wy0 * wx1 * ((vy0 & vx1) ? 1.f : 0.f);
      float c10 = wy1 * wx0 * ((vy1 & vx0) ? 1.f : 0.f);
      float c11 = wy1 * wx1 * ((vy1 & vx1) ? 1.f : 0.f);
      int y0c = min(max(y0, 0), H - 1), y1c = min(max(y1, 0), H - 1);
      int x0c = min(max(x0, 0), W - 1), x1c = min(max(x1, 0), W - 1);
      float v00 = xb[(size_t)(y0c * W + x0c) * C + lane];
      float v01 = xb[(size_t)(y0c * W + x1c) * C + lane];
      float v10 = xb[(size_t)(y1c * W + x0c) * C + lane];
      float v11 = xb[(size_t)(y1c * W + x1c) * C + lane];
      s_samp[q][lane] = m * (c00 * v00 + c01 * v01 + c10 * v10 + c11 * v11);
    }
    __syncthreads();
    if (t < KK) {
      const float* wp = wd + (size_t)(t * C) * COUT + lane;  // lane == co
      const float4* sp = reinterpret_cast<const float4*>(s_samp[q]);
#pragma unroll
      for (int c4 = 0; c4 < C / 4; ++c4) {
        float4 s = sp[c4];
        acc += s.x * wp[(4 * c4 + 0) * COUT] + s.y * wp[(4 * c4 + 1) * COUT] +
               s.z * wp[(4 * c4 + 2) * COUT] + s.w * wp[(4 * c4 + 3) * COUT];
      }
    }
    __syncthreads();
  }
  s_part[tid] = acc;
  __syncthreads();
  if (tid < 64) {
    float v = s_part[tid] + s_part[tid + 64] + s_part[tid + 128] + s_part[tid + 192];
    out[((size_t)(b * (3 * COUT) + br_off + tid)) * HW + y * W + x] = v;
  }
}

// ---------------------------------------------------------------------------
// Launch
// ---------------------------------------------------------------------------
extern "C" void kernel_launch(void* const* d_in, const int* in_sizes, int n_in,
                              void* d_out, int out_size, void* d_ws,
                              size_t ws_size, hipStream_t stream) {
  const float* x = (const float*)d_in[0];
  const float* w_off3 = (const float*)d_in[1];
  const float* b_off3 = (const float*)d_in[2];
  const float* w_mask3 = (const float*)d_in[3];
  const float* b_mask3 = (const float*)d_in[4];
  const float* w_dcn3 = (const float*)d_in[5];
  const float* w_off5 = (const float*)d_in[6];
  const float* b_off5 = (const float*)d_in[7];
  const float* w_mask5 = (const float*)d_in[8];
  const float* b_mask5 = (const float*)d_in[9];
  const float* w_dcn5 = (const float*)d_in[10];
  const float* w_off7 = (const float*)d_in[11];
  const float* b_off7 = (const float*)d_in[12];
  const float* w_mask7 = (const float*)d_in[13];
  const float* b_mask7 = (const float*)d_in[14];
  const float* w_dcn7 = (const float*)d_in[15];
  float* out = (float*)d_out;
  float* ws = (float*)d_ws;

  // Workspace layout (float units, 16B aligned)
  size_t off = 0;
  auto alloc = [&](size_t n) {
    size_t p = off;
    off += (n + 3) & ~(size_t)3;
    return ws + p;
  };
  float* xh = alloc((size_t)B * HW * C);             // fp32 NHWC
  ushort* xhb = (ushort*)alloc((size_t)B * HW * C / 2);  // bf16 NHWC
  float* co3 = alloc((size_t)B * HW * 27);
  float* co5 = alloc((size_t)B * HW * 75);
  float* co7 = alloc((size_t)B * HW * 147);
  ushort* wtb3 = (ushort*)alloc((32 * 9 * C) / 2);
  ushort* wtb5 = (ushort*)alloc((80 * 25 * C) / 2);
  ushort* wtb7 = (ushort*)alloc((160 * 49 * C) / 2);
  float* bc3 = alloc(27);
  float* bc5 = alloc(75);
  float* bc7 = alloc(147);
  float* wd3 = alloc(9 * C * COUT);
  float* wd5 = alloc(25 * C * COUT);
  float* wd7 = alloc(49 * C * COUT);

  // 1) x -> NHWC (fp32 + bf16)
  transpose_nchw_nhwc<<<B * (HW / 64), 256, 0, stream>>>(x, xh, xhb);

  // 2) weight prep
  prep_weights<3, 32><<<128, 256, 0, stream>>>(w_off3, b_off3, w_mask3, b_mask3,
                                               w_dcn3, wtb3, bc3, wd3);
  prep_weights<5, 80><<<256, 256, 0, stream>>>(w_off5, b_off5, w_mask5, b_mask5,
                                               w_dcn5, wtb5, bc5, wd5);
  prep_weights<7, 160><<<512, 256, 0, stream>>>(w_off7, b_off7, w_mask7, b_mask7,
                                                w_dcn7, wtb7, bc7, wd7);

  // 3) offset+mask convs via bf16 MFMA (stores py/px and sigmoided mask)
  //    waves = (M/16) * 2 groups; 4 waves/block -> 400 blocks
  conv_gemm<3, 2><<<400, 256, 0, stream>>>(xhb, wtb3, bc3, co3);
  conv_gemm<5, 5><<<400, 256, 0, stream>>>(xhb, wtb5, bc5, co5);
  conv_gemm<7, 10><<<400, 256, 0, stream>>>(xhb, wtb7, bc7, co7);

  // 4) deformable sampling + einsum (fp32)
  dcn_sample_gemm_kernel<3><<<B * HW, 256, 0, stream>>>(xh, co3, wd3, out, 0);
  dcn_sample_gemm_kernel<5><<<B * HW, 256, 0, stream>>>(xh, co5, wd5, out, 64);
  dcn_sample_gemm_kernel<7><<<B * HW, 256, 0, stream>>>(xh, co7, wd7, out, 128);
}

// Round 3
// 438.895 us; speedup vs baseline: 4.9327x; 1.9945x over previous
//
#include <hip/hip_runtime.h>
#include <math.h>

constexpr int B = 2, C = 64, H = 80, W = 80, HW = H * W, COUT = 64;

typedef __attribute__((ext_vector_type(8))) short short8;   // 8 bf16
typedef __attribute__((ext_vector_type(4))) float f32x4;

__device__ inline ushort f2bf(float f) {
  unsigned u = __float_as_uint(f);
  unsigned r = u + 0x7fff + ((u >> 16) & 1);   // RNE
  return (ushort)(r >> 16);
}
__device__ inline float bf2f(short u) {
  return __uint_as_float(((unsigned)(ushort)u) << 16);
}

// ---------------------------------------------------------------------------
// Transpose x: NCHW fp32 -> NHWC bf16 (MFMA + sampler input).
// ---------------------------------------------------------------------------
__global__ __launch_bounds__(256) void transpose_nchw_nhwc(
    const float* __restrict__ x, ushort* __restrict__ xhb) {
  __shared__ float tile[64][65];
  int blk = blockIdx.x;                 // B * (HW/64) blocks
  int b = blk / (HW / 64);
  int p0 = (blk % (HW / 64)) * 64;
  int lane = threadIdx.x & 63, row = threadIdx.x >> 6;
#pragma unroll
  for (int it = 0; it < 16; ++it) {
    int ci = it * 4 + row;
    tile[ci][lane] = x[(size_t)(b * C + ci) * HW + p0 + lane];
  }
  __syncthreads();
#pragma unroll
  for (int it = 0; it < 16; ++it) {
    int pl = it * 4 + row;
    xhb[((size_t)b * HW + p0 + pl) * C + lane] = f2bf(tile[lane][pl]);
  }
}

// ---------------------------------------------------------------------------
// Weight prep per branch:
//  wtb[n*KDIM + t*C+ci] = bf16 of (n<2KK ? w_off[n][ci][t] : n<C3 ? w_mask : 0)
//  bcomb[co] fp32 combined bias
//  wdt[co*KDIM + t*C+ci] = bf16 of w_dcn[co][ci][t]   (einsum B-matrix)
// ---------------------------------------------------------------------------
template <int K, int NP>
__global__ __launch_bounds__(256) void prep_weights(
    const float* __restrict__ w_off, const float* __restrict__ b_off,
    const float* __restrict__ w_mask, const float* __restrict__ b_mask,
    const float* __restrict__ w_dcn, ushort* __restrict__ wtb,
    float* __restrict__ bcomb, ushort* __restrict__ wdt) {
  constexpr int KK = K * K, C3 = 3 * KK, KDIM = KK * C;
  const int n1 = NP * KDIM;
  const int n2 = C3;
  const int n3 = COUT * KDIM;
  const int total = n1 + n2 + n3;
  for (int i = blockIdx.x * blockDim.x + threadIdx.x; i < total;
       i += gridDim.x * blockDim.x) {
    if (i < n1) {
      int co = i / KDIM;
      int k = i % KDIM;
      int t = k / C;
      int ci = k % C;
      float v = 0.f;
      if (co < 2 * KK) v = w_off[(co * C + ci) * KK + t];
      else if (co < C3) v = w_mask[((co - 2 * KK) * C + ci) * KK + t];
      wtb[i] = f2bf(v);
    } else if (i < n1 + n2) {
      int co = i - n1;
      bcomb[co] = (co < 2 * KK) ? b_off[co] : b_mask[co - 2 * KK];
    } else {
      int j = i - n1 - n2;
      int co = j / KDIM;
      int k = j % KDIM;
      int t = k / C;
      int ci = k % C;
      wdt[j] = f2bf(w_dcn[(co * C + ci) * KK + t]);
    }
  }
}

// ---------------------------------------------------------------------------
// Implicit-im2col bf16 MFMA GEMM for the offset+mask conv.
// Epilogue: bias + base-grid add (offsets) / sigmoid (masks) -> convout[pix][C3]
// ---------------------------------------------------------------------------
template <int K, int NT>
__global__ __launch_bounds__(256) void conv_gemm(
    const ushort* __restrict__ xhb, const ushort* __restrict__ wtb,
    const float* __restrict__ bcomb, float* __restrict__ convout) {
  constexpr int PAD = K / 2, KK = K * K, C3 = 3 * KK, KDIM = KK * C;
  constexpr int NTA = (NT + 1) / 2;
  int tid = threadIdx.x;
  int wid = blockIdx.x * 4 + (tid >> 6);   // global wave id
  int mt = wid >> 1;                       // m-tile (16 pixels)
  int g = wid & 1;                         // n-group
  int j0 = g * NTA;
  int jn = min(NT - j0, NTA);
  int l = tid & 63;
  int lm = l & 15, lk = l >> 4;            // lk in 0..3
  int m0 = mt * 16;
  int b = m0 / HW;
  int rem = m0 % HW;
  int y = rem / W;
  int x0 = rem % W;                        // 16 | m0, 16 | W=80 -> same row
  const ushort* xbase = xhb + (size_t)b * HW * C;
  f32x4 acc[NTA];
#pragma unroll
  for (int j = 0; j < NTA; ++j) acc[j] = f32x4{0.f, 0.f, 0.f, 0.f};

  for (int t = 0; t < KK; ++t) {
    int yy = y + t / K - PAD;
    if ((unsigned)yy >= (unsigned)H) continue;   // wave-uniform
    int xx = x0 + lm + (t % K) - PAD;
    bool vx = (unsigned)xx < (unsigned)W;
    const ushort* aptr = xbase + ((size_t)(yy * W + (vx ? xx : 0))) * C + lk * 8;
    const ushort* wptr = wtb + (size_t)t * C + lk * 8;
#pragma unroll
    for (int half = 0; half < 2; ++half) {
      short8 a = {0, 0, 0, 0, 0, 0, 0, 0};
      if (vx) a = *(const short8*)(aptr + half * 32);
#pragma unroll
      for (int jj = 0; jj < NTA; ++jj) {
        if (jj < jn) {
          int n = (j0 + jj) * 16 + lm;
          short8 bf = *(const short8*)(wptr + half * 32 + (size_t)n * KDIM);
          acc[jj] = __builtin_amdgcn_mfma_f32_16x16x32_bf16(a, bf, acc[jj], 0, 0, 0);
        }
      }
    }
  }

  // Epilogue. D mapping: col(n)=l&15, row(m)=lk*4+r.
#pragma unroll
  for (int jj = 0; jj < NTA; ++jj) {
    if (jj >= jn) continue;
    int co = (j0 + jj) * 16 + lm;
    if (co >= C3) continue;
    float bs = bcomb[co];
    bool isoff = co < 2 * KK;
    int tp = co >> 1;
#pragma unroll
    for (int r = 0; r < 4; ++r) {
      int xr = x0 + lk * 4 + r;
      int pix = m0 + lk * 4 + r;           // = b*HW + y*W + xr
      float v = acc[jj][r] + bs;
      if (isoff) {
        v += (co & 1) ? (float)(xr - PAD + tp % K)    // px
                      : (float)(y - PAD + tp / K);    // py
      } else {
        v = 1.f / (1.f + expf(-v));
      }
      convout[(size_t)pix * C3 + co] = v;
    }
  }
}

// ---------------------------------------------------------------------------
// Fused deformable-sampling + einsum as implicit-A bf16 MFMA GEMM.
//   A[pix][t*C+ci] = mask*bilinear(x) built in registers, packed bf16.
//   B[k][n] = wdt[n*KDIM + k]  (co-major, contiguous k).
// Block: 16 pixels; 4 waves split the KK taps; LDS reduction at the end.
// ---------------------------------------------------------------------------
template <int K>
__global__ __launch_bounds__(256) void dcn_mfma_kernel(
    const ushort* __restrict__ xhb, const float* __restrict__ convout,
    const ushort* __restrict__ wdt, float* __restrict__ out, int br_off) {
  constexpr int KK = K * K, C3 = 3 * KK, KDIM = KK * C;
  constexpr int TPW = (KK + 3) / 4;        // taps per wave (ceil)
  __shared__ float s_red[4][16][65];
  int tid = threadIdx.x, w = tid >> 6, l = tid & 63;
  int lm = l & 15, lk = l >> 4;
  int m0 = blockIdx.x * 16;
  int pix = m0 + lm;
  int b = pix / HW;                        // 16 | HW -> uniform over block
  const ushort* xb = xhb + (size_t)b * HW * C;
  const float* cvp = convout + (size_t)pix * C3;
  f32x4 acc[4];
#pragma unroll
  for (int j = 0; j < 4; ++j) acc[j] = f32x4{0.f, 0.f, 0.f, 0.f};

  for (int tt = 0; tt < TPW; ++tt) {
    int t = w * TPW + tt;                  // wave-uniform
    if (t >= KK) break;
    float py = cvp[2 * t], px = cvp[2 * t + 1], m = cvp[2 * KK + t];
    float fy = floorf(py), fx = floorf(px);
    float wy1 = py - fy, wx1 = px - fx;
    float wy0 = 1.f - wy1, wx0 = 1.f - wx1;
    int y0 = (int)fy, x0 = (int)fx;
    int y1 = y0 + 1, x1 = x0 + 1;
    bool vy0 = (unsigned)y0 < (unsigned)H, vy1 = (unsigned)y1 < (unsigned)H;
    bool vx0 = (unsigned)x0 < (unsigned)W, vx1 = (unsigned)x1 < (unsigned)W;
    float c00 = m * wy0 * wx0 * ((vy0 & vx0) ? 1.f : 0.f);
    float c01 = m * wy0 * wx1 * ((vy0 & vx1) ? 1.f : 0.f);
    float c10 = m * wy1 * wx0 * ((vy1 & vx0) ? 1.f : 0.f);
    float c11 = m * wy1 * wx1 * ((vy1 & vx1) ? 1.f : 0.f);
    int y0c = min(max(y0, 0), H - 1), y1c = min(max(y1, 0), H - 1);
    int x0c = min(max(x0, 0), W - 1), x1c = min(max(x1, 0), W - 1);
    int i00 = (y0c * W + x0c) * C, i01 = (y0c * W + x1c) * C;
    int i10 = (y1c * W + x0c) * C, i11 = (y1c * W + x1c) * C;
#pragma unroll
    for (int half = 0; half < 2; ++half) {
      int cb = half * 32 + lk * 8;
      short8 r00 = *(const short8*)(xb + i00 + cb);
      short8 r01 = *(const short8*)(xb + i01 + cb);
      short8 r10 = *(const short8*)(xb + i10 + cb);
      short8 r11 = *(const short8*)(xb + i11 + cb);
      short8 a;
#pragma unroll
      for (int e = 0; e < 8; ++e) {
        float v = c00 * bf2f(r00[e]) + c01 * bf2f(r01[e]) +
                  c10 * bf2f(r10[e]) + c11 * bf2f(r11[e]);
        a[e] = (short)f2bf(v);
      }
      int kbase = t * C + cb;
#pragma unroll
      for (int j = 0; j < 4; ++j) {
        short8 bf = *(const short8*)(wdt + (size_t)(j * 16 + lm) * KDIM + kbase);
        acc[j] = __builtin_amdgcn_mfma_f32_16x16x32_bf16(a, bf, acc[j], 0, 0, 0);
      }
    }
  }

  // K-split reduction across the 4 waves. D map: col=lm(co), row=lk*4+r(pixel).
#pragma unroll
  for (int j = 0; j < 4; ++j)
#pragma unroll
    for (int r = 0; r < 4; ++r)
      s_red[w][lk * 4 + r][j * 16 + lm] = acc[j][r];
  __syncthreads();
  int rem0 = m0 - b * HW;
#pragma unroll
  for (int i = 0; i < 4; ++i) {
    int idx = i * 256 + tid;
    int mrow = idx & 15, co = idx >> 4;
    float v = s_red[0][mrow][co] + s_red[1][mrow][co] +
              s_red[2][mrow][co] + s_red[3][mrow][co];
    out[(size_t)(b * (3 * COUT) + br_off + co) * HW + rem0 + mrow] = v;
  }
}

// ---------------------------------------------------------------------------
// Launch
// ---------------------------------------------------------------------------
extern "C" void kernel_launch(void* const* d_in, const int* in_sizes, int n_in,
                              void* d_out, int out_size, void* d_ws,
                              size_t ws_size, hipStream_t stream) {
  const float* x = (const float*)d_in[0];
  const float* w_off3 = (const float*)d_in[1];
  const float* b_off3 = (const float*)d_in[2];
  const float* w_mask3 = (const float*)d_in[3];
  const float* b_mask3 = (const float*)d_in[4];
  const float* w_dcn3 = (const float*)d_in[5];
  const float* w_off5 = (const float*)d_in[6];
  const float* b_off5 = (const float*)d_in[7];
  const float* w_mask5 = (const float*)d_in[8];
  const float* b_mask5 = (const float*)d_in[9];
  const float* w_dcn5 = (const float*)d_in[10];
  const float* w_off7 = (const float*)d_in[11];
  const float* b_off7 = (const float*)d_in[12];
  const float* w_mask7 = (const float*)d_in[13];
  const float* b_mask7 = (const float*)d_in[14];
  const float* w_dcn7 = (const float*)d_in[15];
  float* out = (float*)d_out;
  float* ws = (float*)d_ws;

  // Workspace layout (float units, 16B aligned)
  size_t off = 0;
  auto alloc = [&](size_t n) {
    size_t p = off;
    off += (n + 3) & ~(size_t)3;
    return ws + p;
  };
  ushort* xhb = (ushort*)alloc((size_t)B * HW * C / 2);  // bf16 NHWC
  float* co3 = alloc((size_t)B * HW * 27);
  float* co5 = alloc((size_t)B * HW * 75);
  float* co7 = alloc((size_t)B * HW * 147);
  ushort* wtb3 = (ushort*)alloc((32 * 9 * C) / 2);
  ushort* wtb5 = (ushort*)alloc((80 * 25 * C) / 2);
  ushort* wtb7 = (ushort*)alloc((160 * 49 * C) / 2);
  float* bc3 = alloc(27);
  float* bc5 = alloc(75);
  float* bc7 = alloc(147);
  ushort* wdt3 = (ushort*)alloc((COUT * 9 * C) / 2);
  ushort* wdt5 = (ushort*)alloc((COUT * 25 * C) / 2);
  ushort* wdt7 = (ushort*)alloc((COUT * 49 * C) / 2);

  // 1) x -> NHWC bf16
  transpose_nchw_nhwc<<<B * (HW / 64), 256, 0, stream>>>(x, xhb);

  // 2) weight prep
  prep_weights<3, 32><<<128, 256, 0, stream>>>(w_off3, b_off3, w_mask3, b_mask3,
                                               w_dcn3, wtb3, bc3, wdt3);
  prep_weights<5, 80><<<256, 256, 0, stream>>>(w_off5, b_off5, w_mask5, b_mask5,
                                               w_dcn5, wtb5, bc5, wdt5);
  prep_weights<7, 160><<<512, 256, 0, stream>>>(w_off7, b_off7, w_mask7, b_mask7,
                                                w_dcn7, wtb7, bc7, wdt7);

  // 3) offset+mask convs via bf16 MFMA (stores py/px and sigmoided mask)
  conv_gemm<3, 2><<<400, 256, 0, stream>>>(xhb, wtb3, bc3, co3);
  conv_gemm<5, 5><<<400, 256, 0, stream>>>(xhb, wtb5, bc5, co5);
  conv_gemm<7, 10><<<400, 256, 0, stream>>>(xhb, wtb7, bc7, co7);

  // 4) fused deformable sampling + einsum via bf16 MFMA
  dcn_mfma_kernel<3><<<B * HW / 16, 256, 0, stream>>>(xhb, co3, wdt3, out, 0);
  dcn_mfma_kernel<5><<<B * HW / 16, 256, 0, stream>>>(xhb, co5, wdt5, out, 64);
  dcn_mfma_kernel<7><<<B * HW / 16, 256, 0, stream>>>(xhb, co7, wdt7, out, 128);
}

// Round 4
// 309.109 us; speedup vs baseline: 7.0038x; 1.4199x over previous
//
#include <hip/hip_runtime.h>
#include <math.h>

constexpr int B = 2, C = 64, H = 80, W = 80, HW = H * W, COUT = 64;

typedef __attribute__((ext_vector_type(8))) short short8;   // 8 bf16
typedef __attribute__((ext_vector_type(4))) float f32x4;

__device__ inline ushort f2bf(float f) {
  unsigned u = __float_as_uint(f);
  unsigned r = u + 0x7fff + ((u >> 16) & 1);   // RNE
  return (ushort)(r >> 16);
}
__device__ inline float bf2f(short u) {
  return __uint_as_float(((unsigned)(ushort)u) << 16);
}

// ---------------------------------------------------------------------------
// Transpose x: NCHW fp32 -> NHWC bf16 (MFMA + sampler input).
// ---------------------------------------------------------------------------
__global__ __launch_bounds__(256) void transpose_nchw_nhwc(
    const float* __restrict__ x, ushort* __restrict__ xhb) {
  __shared__ float tile[64][65];
  int blk = blockIdx.x;                 // B * (HW/64) blocks
  int b = blk / (HW / 64);
  int p0 = (blk % (HW / 64)) * 64;
  int lane = threadIdx.x & 63, row = threadIdx.x >> 6;
#pragma unroll
  for (int it = 0; it < 16; ++it) {
    int ci = it * 4 + row;
    tile[ci][lane] = x[(size_t)(b * C + ci) * HW + p0 + lane];
  }
  __syncthreads();
#pragma unroll
  for (int it = 0; it < 16; ++it) {
    int pl = it * 4 + row;
    xhb[((size_t)b * HW + p0 + pl) * C + lane] = f2bf(tile[lane][pl]);
  }
}

// ---------------------------------------------------------------------------
// Weight prep per branch — B matrices pre-swizzled into per-lane MFMA
// fragment order so kernel-side loads are fully coalesced:
//  wtbs[((t*2+half)*NT + nt)*512 + l*8 + e] = Bconv[k][n],
//      n = nt*16 + (l&15), k(ci) = half*32 + (l>>4)*8 + e, tap t.
//  wdts[((t*2+half)*4 + jt)*512 + l*8 + e] = w_dcn fragment, co = jt*16+(l&15).
//  bcomb[co] fp32 combined bias.
// ---------------------------------------------------------------------------
template <int K, int NT>
__global__ __launch_bounds__(256) void prep_weights(
    const float* __restrict__ w_off, const float* __restrict__ b_off,
    const float* __restrict__ w_mask, const float* __restrict__ b_mask,
    const float* __restrict__ w_dcn, ushort* __restrict__ wtbs,
    float* __restrict__ bcomb, ushort* __restrict__ wdts) {
  constexpr int KK = K * K, C3 = 3 * KK;
  const int n1 = KK * 2 * NT * 512;
  const int n2 = C3;
  const int n3 = KK * 2 * 4 * 512;
  const int total = n1 + n2 + n3;
  for (int i = blockIdx.x * blockDim.x + threadIdx.x; i < total;
       i += gridDim.x * blockDim.x) {
    if (i < n1) {
      int e = i & 7, l = (i >> 3) & 63;
      int blk512 = i >> 9;
      int nt = blk512 % NT, th = blk512 / NT;
      int half = th & 1, t = th >> 1;
      int n = nt * 16 + (l & 15);
      int ci = half * 32 + (l >> 4) * 8 + e;
      float v = 0.f;
      if (n < 2 * KK) v = w_off[(n * C + ci) * KK + t];
      else if (n < C3) v = w_mask[((n - 2 * KK) * C + ci) * KK + t];
      wtbs[i] = f2bf(v);
    } else if (i < n1 + n2) {
      int co = i - n1;
      bcomb[co] = (co < 2 * KK) ? b_off[co] : b_mask[co - 2 * KK];
    } else {
      int j = i - n1 - n2;
      int e = j & 7, l = (j >> 3) & 63;
      int blk512 = j >> 9;
      int jt = blk512 & 3, th = blk512 >> 2;
      int half = th & 1, t = th >> 1;
      int co = jt * 16 + (l & 15);
      int ci = half * 32 + (l >> 4) * 8 + e;
      wdts[j] = f2bf(w_dcn[(co * C + ci) * KK + t]);
    }
  }
}

// ---------------------------------------------------------------------------
// Implicit-im2col bf16 MFMA GEMM for the offset+mask conv.
// Wave = one 16-pixel m-tile x NTA n-tiles; NG n-groups for occupancy.
// ---------------------------------------------------------------------------
template <int K, int NT, int NTA>
__global__ __launch_bounds__(256) void conv_gemm(
    const ushort* __restrict__ xhb, const ushort* __restrict__ wtbs,
    const float* __restrict__ bcomb, float* __restrict__ convout) {
  constexpr int PAD = K / 2, KK = K * K, C3 = 3 * KK;
  constexpr int NG = (NT + NTA - 1) / NTA;
  int tid = threadIdx.x;
  int wid = blockIdx.x * 4 + (tid >> 6);   // global wave id
  int mt = wid / NG;
  int g = wid % NG;
  int j0 = g * NTA;
  int jn = min(NT - j0, NTA);
  int l = tid & 63;
  int lm = l & 15, lk = l >> 4;
  int m0 = mt * 16;
  int b = m0 / HW;
  int rem = m0 % HW;
  int y = rem / W;
  int x0 = rem % W;                        // 16 | W=80 -> whole tile same row
  const ushort* xbase = xhb + (size_t)b * HW * C;
  f32x4 acc[NTA];
#pragma unroll
  for (int j = 0; j < NTA; ++j) acc[j] = f32x4{0.f, 0.f, 0.f, 0.f};

  for (int t = 0; t < KK; ++t) {
    int yy = y + t / K - PAD;
    if ((unsigned)yy >= (unsigned)H) continue;   // wave-uniform
    int xx = x0 + lm + (t % K) - PAD;
    bool vx = (unsigned)xx < (unsigned)W;
    const ushort* aptr = xbase + ((size_t)(yy * W + (vx ? xx : 0))) * C + lk * 8;
    const ushort* fbase = wtbs + (size_t)(t * 2) * NT * 512 + l * 8;
#pragma unroll
    for (int half = 0; half < 2; ++half) {
      short8 a = {0, 0, 0, 0, 0, 0, 0, 0};
      if (vx) a = *(const short8*)(aptr + half * 32);
#pragma unroll
      for (int jj = 0; jj < NTA; ++jj) {
        if (jj < jn) {
          short8 bf = *(const short8*)(fbase + (size_t)(half * NT + j0 + jj) * 512);
          acc[jj] = __builtin_amdgcn_mfma_f32_16x16x32_bf16(a, bf, acc[jj], 0, 0, 0);
        }
      }
    }
  }

  // Epilogue. D mapping: col(n)=lm, row(m)=lk*4+r.
#pragma unroll
  for (int jj = 0; jj < NTA; ++jj) {
    if (jj >= jn) continue;
    int co = (j0 + jj) * 16 + lm;
    if (co >= C3) continue;
    float bs = bcomb[co];
    bool isoff = co < 2 * KK;
    int tp = co >> 1;
#pragma unroll
    for (int r = 0; r < 4; ++r) {
      int xr = x0 + lk * 4 + r;
      int pix = m0 + lk * 4 + r;
      float v = acc[jj][r] + bs;
      if (isoff) {
        v += (co & 1) ? (float)(xr - PAD + tp % K)    // px
                      : (float)(y - PAD + tp / K);    // py
      } else {
        v = 1.f / (1.f + expf(-v));
      }
      convout[(size_t)pix * C3 + co] = v;
    }
  }
}

// ---------------------------------------------------------------------------
// Fused deformable-sampling + einsum as implicit-A bf16 MFMA GEMM.
// Block: 16 pixels; 4 waves split KK taps; convout staged in LDS; swizzled
// coalesced B-fragments; LDS reduction at the end.
// ---------------------------------------------------------------------------
template <int K>
__global__ __launch_bounds__(256) void dcn_mfma_kernel(
    const ushort* __restrict__ xhb, const float* __restrict__ convout,
    const ushort* __restrict__ wdts, float* __restrict__ out, int br_off) {
  constexpr int KK = K * K, C3 = 3 * KK;
  constexpr int TPW = (KK + 3) / 4;        // taps per wave (ceil)
  __shared__ float s_cv[16 * C3];
  __shared__ float s_red[4][16][65];
  int tid = threadIdx.x, w = tid >> 6, l = tid & 63;
  int lm = l & 15, lk = l >> 4;
  int m0 = blockIdx.x * 16;
  int b = m0 / HW;                         // 16 | HW -> uniform over block
  const ushort* xb = xhb + (size_t)b * HW * C;
  for (int idx = tid; idx < 16 * C3; idx += 256)
    s_cv[idx] = convout[(size_t)m0 * C3 + idx];
  __syncthreads();
  const float* cp = s_cv + lm * C3;
  f32x4 acc[4];
#pragma unroll
  for (int j = 0; j < 4; ++j) acc[j] = f32x4{0.f, 0.f, 0.f, 0.f};

  for (int tt = 0; tt < TPW; ++tt) {
    int t = w * TPW + tt;                  // wave-uniform
    if (t >= KK) break;
    float py = cp[2 * t], px = cp[2 * t + 1], m = cp[2 * KK + t];
    float fy = floorf(py), fx = floorf(px);
    float wy1 = py - fy, wx1 = px - fx;
    float wy0 = 1.f - wy1, wx0 = 1.f - wx1;
    int y0 = (int)fy, x0 = (int)fx;
    int y1 = y0 + 1, x1 = x0 + 1;
    bool vy0 = (unsigned)y0 < (unsigned)H, vy1 = (unsigned)y1 < (unsigned)H;
    bool vx0 = (unsigned)x0 < (unsigned)W, vx1 = (unsigned)x1 < (unsigned)W;
    float c00 = m * wy0 * wx0 * ((vy0 & vx0) ? 1.f : 0.f);
    float c01 = m * wy0 * wx1 * ((vy0 & vx1) ? 1.f : 0.f);
    float c10 = m * wy1 * wx0 * ((vy1 & vx0) ? 1.f : 0.f);
    float c11 = m * wy1 * wx1 * ((vy1 & vx1) ? 1.f : 0.f);
    int y0c = min(max(y0, 0), H - 1), y1c = min(max(y1, 0), H - 1);
    int x0c = min(max(x0, 0), W - 1), x1c = min(max(x1, 0), W - 1);
    int i00 = (y0c * W + x0c) * C, i01 = (y0c * W + x1c) * C;
    int i10 = (y1c * W + x0c) * C, i11 = (y1c * W + x1c) * C;
#pragma unroll
    for (int half = 0; half < 2; ++half) {
      int cb = half * 32 + lk * 8;
      short8 r00 = *(const short8*)(xb + i00 + cb);
      short8 r01 = *(const short8*)(xb + i01 + cb);
      short8 r10 = *(const short8*)(xb + i10 + cb);
      short8 r11 = *(const short8*)(xb + i11 + cb);
      short8 a;
#pragma unroll
      for (int e = 0; e < 8; ++e) {
        float v = fmaf(c00, bf2f(r00[e]),
                  fmaf(c01, bf2f(r01[e]),
                  fmaf(c10, bf2f(r10[e]), c11 * bf2f(r11[e]))));
        a[e] = (short)f2bf(v);
      }
      const ushort* fbase = wdts + (size_t)((t * 2 + half) * 4) * 512 + l * 8;
#pragma unroll
      for (int j = 0; j < 4; ++j) {
        short8 bf = *(const short8*)(fbase + j * 512);
        acc[j] = __builtin_amdgcn_mfma_f32_16x16x32_bf16(a, bf, acc[j], 0, 0, 0);
      }
    }
  }

  // K-split reduction across the 4 waves. D map: col=lm(co), row=lk*4+r(pixel).
#pragma unroll
  for (int j = 0; j < 4; ++j)
#pragma unroll
    for (int r = 0; r < 4; ++r)
      s_red[w][lk * 4 + r][j * 16 + lm] = acc[j][r];
  __syncthreads();
  int rem0 = m0 - b * HW;
#pragma unroll
  for (int i = 0; i < 4; ++i) {
    int idx = i * 256 + tid;
    int mrow = idx & 15, co = idx >> 4;
    float v = s_red[0][mrow][co] + s_red[1][mrow][co] +
              s_red[2][mrow][co] + s_red[3][mrow][co];
    out[(size_t)(b * (3 * COUT) + br_off + co) * HW + rem0 + mrow] = v;
  }
}

// ---------------------------------------------------------------------------
// Launch
// ---------------------------------------------------------------------------
extern "C" void kernel_launch(void* const* d_in, const int* in_sizes, int n_in,
                              void* d_out, int out_size, void* d_ws,
                              size_t ws_size, hipStream_t stream) {
  const float* x = (const float*)d_in[0];
  const float* w_off3 = (const float*)d_in[1];
  const float* b_off3 = (const float*)d_in[2];
  const float* w_mask3 = (const float*)d_in[3];
  const float* b_mask3 = (const float*)d_in[4];
  const float* w_dcn3 = (const float*)d_in[5];
  const float* w_off5 = (const float*)d_in[6];
  const float* b_off5 = (const float*)d_in[7];
  const float* w_mask5 = (const float*)d_in[8];
  const float* b_mask5 = (const float*)d_in[9];
  const float* w_dcn5 = (const float*)d_in[10];
  const float* w_off7 = (const float*)d_in[11];
  const float* b_off7 = (const float*)d_in[12];
  const float* w_mask7 = (const float*)d_in[13];
  const float* b_mask7 = (const float*)d_in[14];
  const float* w_dcn7 = (const float*)d_in[15];
  float* out = (float*)d_out;
  float* ws = (float*)d_ws;

  // Workspace layout (float units, 16B aligned)
  size_t off = 0;
  auto alloc = [&](size_t n) {
    size_t p = off;
    off += (n + 3) & ~(size_t)3;
    return ws + p;
  };
  ushort* xhb = (ushort*)alloc((size_t)B * HW * C / 2);  // bf16 NHWC
  float* co3 = alloc((size_t)B * HW * 27);
  float* co5 = alloc((size_t)B * HW * 75);
  float* co7 = alloc((size_t)B * HW * 147);
  ushort* wtbs3 = (ushort*)alloc(9 * 2 * 2 * 512 / 2);
  ushort* wtbs5 = (ushort*)alloc(25 * 2 * 5 * 512 / 2);
  ushort* wtbs7 = (ushort*)alloc(49 * 2 * 10 * 512 / 2);
  float* bc3 = alloc(27);
  float* bc5 = alloc(75);
  float* bc7 = alloc(147);
  ushort* wdts3 = (ushort*)alloc(9 * 2 * 4 * 512 / 2);
  ushort* wdts5 = (ushort*)alloc(25 * 2 * 4 * 512 / 2);
  ushort* wdts7 = (ushort*)alloc(49 * 2 * 4 * 512 / 2);

  // 1) x -> NHWC bf16
  transpose_nchw_nhwc<<<B * (HW / 64), 256, 0, stream>>>(x, xhb);

  // 2) weight prep (pre-swizzled MFMA fragments)
  prep_weights<3, 2><<<64, 256, 0, stream>>>(w_off3, b_off3, w_mask3, b_mask3,
                                             w_dcn3, wtbs3, bc3, wdts3);
  prep_weights<5, 5><<<128, 256, 0, stream>>>(w_off5, b_off5, w_mask5, b_mask5,
                                              w_dcn5, wtbs5, bc5, wdts5);
  prep_weights<7, 10><<<256, 256, 0, stream>>>(w_off7, b_off7, w_mask7, b_mask7,
                                               w_dcn7, wtbs7, bc7, wdts7);

  // 3) offset+mask convs via bf16 MFMA (stores py/px and sigmoided mask)
  //    waves = Mtiles(800) * NG; blocks = waves/4
  conv_gemm<3, 2, 1><<<400, 256, 0, stream>>>(xhb, wtbs3, bc3, co3);   // NG=2
  conv_gemm<5, 5, 2><<<600, 256, 0, stream>>>(xhb, wtbs5, bc5, co5);   // NG=3
  conv_gemm<7, 10, 2><<<1000, 256, 0, stream>>>(xhb, wtbs7, bc7, co7); // NG=5

  // 4) fused deformable sampling + einsum via bf16 MFMA
  dcn_mfma_kernel<3><<<B * HW / 16, 256, 0, stream>>>(xhb, co3, wdts3, out, 0);
  dcn_mfma_kernel<5><<<B * HW / 16, 256, 0, stream>>>(xhb, co5, wdts5, out, 64);
  dcn_mfma_kernel<7><<<B * HW / 16, 256, 0, stream>>>(xhb, co7, wdts7, out, 128);
}

// Round 5
// 264.950 us; speedup vs baseline: 8.1711x; 1.1667x over previous
//
#include <hip/hip_runtime.h>
#include <math.h>

constexpr int B = 2, C = 64, H = 80, W = 80, HW = H * W, COUT = 64;

typedef __attribute__((ext_vector_type(8))) short short8;   // 8 bf16
typedef __attribute__((ext_vector_type(4))) float f32x4;
typedef __attribute__((ext_vector_type(2))) float f32x2;

__device__ inline ushort f2bf(float f) {
  unsigned u = __float_as_uint(f);
  unsigned r = u + 0x7fff + ((u >> 16) & 1);   // RNE
  return (ushort)(r >> 16);
}

__device__ inline f32x2 unpack_bf2(unsigned u) {
  f32x2 r;
  r.x = __uint_as_float(u << 16);
  r.y = __uint_as_float(u & 0xffff0000u);
  return r;
}

// bilinear-combine 2 bf16 channels x 4 corners, repack to 2 bf16 (1 v_perm)
__device__ inline unsigned bilin_pack(unsigned a, unsigned b, unsigned c,
                                      unsigned d, f32x2 c00, f32x2 c01,
                                      f32x2 c10, f32x2 c11) {
  f32x2 p = unpack_bf2(a) * c00;
  p += unpack_bf2(b) * c01;
  p += unpack_bf2(c) * c10;
  p += unpack_bf2(d) * c11;
  unsigned lo = __float_as_uint(p.x) + 0x8000u;
  unsigned hi = __float_as_uint(p.y) + 0x8000u;
  return __builtin_amdgcn_perm(hi, lo, 0x07060302);
}

// ---------------------------------------------------------------------------
// Weight prep body (grid-stride over this branch's swizzled tables).
//  wtbs[((t*2+half)*NT + nt)*512 + l*8 + e]  conv B fragments (lane-ordered)
//  wdts[((t*2+half)*4 + jt)*512 + l*8 + e]   dcn  B fragments
//  bcomb[co] fp32 combined bias
// ---------------------------------------------------------------------------
template <int K, int NT>
__device__ void prep_body(int pb, int nblk, const float* __restrict__ w_off,
                          const float* __restrict__ b_off,
                          const float* __restrict__ w_mask,
                          const float* __restrict__ b_mask,
                          const float* __restrict__ w_dcn,
                          ushort* __restrict__ wtbs, float* __restrict__ bcomb,
                          ushort* __restrict__ wdts) {
  constexpr int KK = K * K, C3 = 3 * KK;
  const int n1 = KK * 2 * NT * 512;
  const int n2 = C3;
  const int n3 = KK * 2 * 4 * 512;
  const int total = n1 + n2 + n3;
  for (int i = pb * 256 + threadIdx.x; i < total; i += nblk * 256) {
    if (i < n1) {
      int e = i & 7, l = (i >> 3) & 63;
      int blk512 = i >> 9;
      int nt = blk512 % NT, th = blk512 / NT;
      int half = th & 1, t = th >> 1;
      int n = nt * 16 + (l & 15);
      int ci = half * 32 + (l >> 4) * 8 + e;
      float v = 0.f;
      if (n < 2 * KK) v = w_off[(n * C + ci) * KK + t];
      else if (n < C3) v = w_mask[((n - 2 * KK) * C + ci) * KK + t];
      wtbs[i] = f2bf(v);
    } else if (i < n1 + n2) {
      int co = i - n1;
      bcomb[co] = (co < 2 * KK) ? b_off[co] : b_mask[co - 2 * KK];
    } else {
      int j = i - n1 - n2;
      int e = j & 7, l = (j >> 3) & 63;
      int blk512 = j >> 9;
      int jt = blk512 & 3, th = blk512 >> 2;
      int half = th & 1, t = th >> 1;
      int co = jt * 16 + (l & 15);
      int ci = half * 32 + (l >> 4) * 8 + e;
      wdts[j] = f2bf(w_dcn[(co * C + ci) * KK + t]);
    }
  }
}

// ---------------------------------------------------------------------------
// setup_all: blocks 0..199 transpose NCHW->NHWC bf16; blocks 200..455 prep.
// ---------------------------------------------------------------------------
__global__ __launch_bounds__(256) void setup_all(
    const float* __restrict__ x, ushort* __restrict__ xhb,
    const float* __restrict__ w_off3, const float* __restrict__ b_off3,
    const float* __restrict__ w_mask3, const float* __restrict__ b_mask3,
    const float* __restrict__ w_dcn3, ushort* __restrict__ wtbs3,
    float* __restrict__ bc3, ushort* __restrict__ wdts3,
    const float* __restrict__ w_off5, const float* __restrict__ b_off5,
    const float* __restrict__ w_mask5, const float* __restrict__ b_mask5,
    const float* __restrict__ w_dcn5, ushort* __restrict__ wtbs5,
    float* __restrict__ bc5, ushort* __restrict__ wdts5,
    const float* __restrict__ w_off7, const float* __restrict__ b_off7,
    const float* __restrict__ w_mask7, const float* __restrict__ b_mask7,
    const float* __restrict__ w_dcn7, ushort* __restrict__ wtbs7,
    float* __restrict__ bc7, ushort* __restrict__ wdts7) {
  __shared__ float tile[64][65];
  int blk = blockIdx.x;
  if (blk < 200) {
    int b = blk / (HW / 64);
    int p0 = (blk % (HW / 64)) * 64;
    int lane = threadIdx.x & 63, row = threadIdx.x >> 6;
#pragma unroll
    for (int it = 0; it < 16; ++it) {
      int ci = it * 4 + row;
      tile[ci][lane] = x[(size_t)(b * C + ci) * HW + p0 + lane];
    }
    __syncthreads();
#pragma unroll
    for (int it = 0; it < 16; ++it) {
      int pl = it * 4 + row;
      xhb[((size_t)b * HW + p0 + pl) * C + lane] = f2bf(tile[lane][pl]);
    }
  } else {
    int pb = blk - 200;
    prep_body<7, 10>(pb, 256, w_off7, b_off7, w_mask7, b_mask7, w_dcn7, wtbs7,
                     bc7, wdts7);
    prep_body<5, 5>(pb, 256, w_off5, b_off5, w_mask5, b_mask5, w_dcn5, wtbs5,
                    bc5, wdts5);
    prep_body<3, 2>(pb, 256, w_off3, b_off3, w_mask3, b_mask3, w_dcn3, wtbs3,
                    bc3, wdts3);
  }
}

// ---------------------------------------------------------------------------
// Conv body: implicit-im2col bf16 MFMA GEMM, branchless predicated K-loop.
// Wave = one 16-pixel m-tile x NTA n-tiles; NG n-groups.
// ---------------------------------------------------------------------------
template <int K, int NT, int NTA>
__device__ __forceinline__ void conv_body(int blk,
                                          const ushort* __restrict__ xhb,
                                          const ushort* __restrict__ wtbs,
                                          const float* __restrict__ bcomb,
                                          float* __restrict__ convout) {
  constexpr int PAD = K / 2, KK = K * K, C3 = 3 * KK;
  constexpr int NG = (NT + NTA - 1) / NTA;
  int tid = threadIdx.x;
  int wid = blk * 4 + (tid >> 6);
  int mt = wid / NG;
  int g = wid % NG;
  int j0 = g * NTA;
  int jn = min(NT - j0, NTA);
  int l = tid & 63;
  int lm = l & 15, lk = l >> 4;
  int m0 = mt * 16;
  int b = m0 / HW;
  int rem = m0 % HW;
  int y = rem / W;
  int x0 = rem % W;                        // 16 | W=80 -> whole tile same row
  const ushort* xbase = xhb + (size_t)b * HW * C;
  f32x4 acc[NTA];
#pragma unroll
  for (int j = 0; j < NTA; ++j) acc[j] = f32x4{0.f, 0.f, 0.f, 0.f};

  const short8 zero8 = {0, 0, 0, 0, 0, 0, 0, 0};
#pragma unroll
  for (int ky = 0; ky < K; ++ky) {
    int yy = y + ky - PAD;
    bool vy = (unsigned)yy < (unsigned)H;
    const ushort* xrow = xbase + (size_t)(vy ? yy : 0) * W * C;
#pragma unroll
    for (int kx = 0; kx < K; ++kx) {
      int t = ky * K + kx;
      int xx = x0 + lm + kx - PAD;
      bool v = vy && ((unsigned)xx < (unsigned)W);
      const ushort* aptr = xrow + (size_t)(v ? xx : 0) * C + lk * 8;
      short8 a0 = *(const short8*)(aptr);
      short8 a1 = *(const short8*)(aptr + 32);
      if (!v) { a0 = zero8; a1 = zero8; }
      const ushort* fbase = wtbs + (size_t)(t * 2) * NT * 512 + l * 8;
#pragma unroll
      for (int jj = 0; jj < NTA; ++jj)
        if (jj < jn) {
          short8 bf = *(const short8*)(fbase + (size_t)(j0 + jj) * 512);
          acc[jj] = __builtin_amdgcn_mfma_f32_16x16x32_bf16(a0, bf, acc[jj], 0, 0, 0);
        }
#pragma unroll
      for (int jj = 0; jj < NTA; ++jj)
        if (jj < jn) {
          short8 bf = *(const short8*)(fbase + (size_t)(NT + j0 + jj) * 512);
          acc[jj] = __builtin_amdgcn_mfma_f32_16x16x32_bf16(a1, bf, acc[jj], 0, 0, 0);
        }
    }
  }

  // Epilogue. D mapping: col(n)=lm, row(m)=lk*4+r.
#pragma unroll
  for (int jj = 0; jj < NTA; ++jj) {
    if (jj >= jn) continue;
    int co = (j0 + jj) * 16 + lm;
    if (co >= C3) continue;
    float bs = bcomb[co];
    bool isoff = co < 2 * KK;
    int tp = co >> 1;
#pragma unroll
    for (int r = 0; r < 4; ++r) {
      int xr = x0 + lk * 4 + r;
      int pix = m0 + lk * 4 + r;
      float v = acc[jj][r] + bs;
      if (isoff) {
        v += (co & 1) ? (float)(xr - PAD + tp % K)    // px
                      : (float)(y - PAD + tp / K);    // py
      } else {
        v = 1.f / (1.f + expf(-v));
      }
      convout[(size_t)pix * C3 + co] = v;
    }
  }
}

__global__ __launch_bounds__(256, 4) void conv_all(
    const ushort* __restrict__ xhb,
    const ushort* __restrict__ wtbs7, const float* __restrict__ bc7, float* __restrict__ co7,
    const ushort* __restrict__ wtbs5, const float* __restrict__ bc5, float* __restrict__ co5,
    const ushort* __restrict__ wtbs3, const float* __restrict__ bc3, float* __restrict__ co3) {
  int blk = blockIdx.x;
  if (blk < 1000) conv_body<7, 10, 2>(blk, xhb, wtbs7, bc7, co7);
  else if (blk < 1600) conv_body<5, 5, 2>(blk - 1000, xhb, wtbs5, bc5, co5);
  else conv_body<3, 2, 2>(blk - 1600, xhb, wtbs3, bc3, co3);
}

// ---------------------------------------------------------------------------
// DCN body: fused deformable-sampling + einsum as implicit-A bf16 MFMA GEMM.
// Block = 16 pixels; 4 waves split KK taps; LDS K-split reduction.
// ---------------------------------------------------------------------------
template <int K>
__device__ __forceinline__ void dcn_body(int blk, const ushort* __restrict__ xhb,
                                         const float* __restrict__ convout,
                                         const ushort* __restrict__ wdts,
                                         float* __restrict__ out, int br_off,
                                         float* s_cv, float (*s_red)[16][65]) {
  constexpr int KK = K * K, C3 = 3 * KK;
  constexpr int TPW = (KK + 3) / 4;
  int tid = threadIdx.x, w = tid >> 6, l = tid & 63;
  int lm = l & 15, lk = l >> 4;
  int m0 = blk * 16;
  int b = m0 / HW;
  const ushort* xb = xhb + (size_t)b * HW * C;
  for (int idx = tid; idx < 16 * C3; idx += 256)
    s_cv[idx] = convout[(size_t)m0 * C3 + idx];
  __syncthreads();
  const float* cp = s_cv + lm * C3;
  f32x4 acc[4];
#pragma unroll
  for (int j = 0; j < 4; ++j) acc[j] = f32x4{0.f, 0.f, 0.f, 0.f};

  for (int tt = 0; tt < TPW; ++tt) {
    int t = w * TPW + tt;                  // wave-uniform
    if (t >= KK) break;
    float py = cp[2 * t], px = cp[2 * t + 1], m = cp[2 * KK + t];
    float fy = floorf(py), fx = floorf(px);
    float wy1 = py - fy, wx1 = px - fx;
    float wy0 = 1.f - wy1, wx0 = 1.f - wx1;
    int y0 = (int)fy, x0 = (int)fx;
    int y1 = y0 + 1, x1 = x0 + 1;
    bool vy0 = (unsigned)y0 < (unsigned)H, vy1 = (unsigned)y1 < (unsigned)H;
    bool vx0 = (unsigned)x0 < (unsigned)W, vx1 = (unsigned)x1 < (unsigned)W;
    float c00 = m * wy0 * wx0 * ((vy0 & vx0) ? 1.f : 0.f);
    float c01 = m * wy0 * wx1 * ((vy0 & vx1) ? 1.f : 0.f);
    float c10 = m * wy1 * wx0 * ((vy1 & vx0) ? 1.f : 0.f);
    float c11 = m * wy1 * wx1 * ((vy1 & vx1) ? 1.f : 0.f);
    f32x2 C00 = {c00, c00}, C01 = {c01, c01}, C10 = {c10, c10}, C11 = {c11, c11};
    int y0c = min(max(y0, 0), H - 1), y1c = min(max(y1, 0), H - 1);
    int x0c = min(max(x0, 0), W - 1), x1c = min(max(x1, 0), W - 1);
    int i00 = (y0c * W + x0c) * C, i01 = (y0c * W + x1c) * C;
    int i10 = (y1c * W + x0c) * C, i11 = (y1c * W + x1c) * C;
#pragma unroll
    for (int half = 0; half < 2; ++half) {
      int cb = half * 32 + lk * 8;
      uint4 u00 = *(const uint4*)(xb + i00 + cb);
      uint4 u01 = *(const uint4*)(xb + i01 + cb);
      uint4 u10 = *(const uint4*)(xb + i10 + cb);
      uint4 u11 = *(const uint4*)(xb + i11 + cb);
      uint4 ap;
      ap.x = bilin_pack(u00.x, u01.x, u10.x, u11.x, C00, C01, C10, C11);
      ap.y = bilin_pack(u00.y, u01.y, u10.y, u11.y, C00, C01, C10, C11);
      ap.z = bilin_pack(u00.z, u01.z, u10.z, u11.z, C00, C01, C10, C11);
      ap.w = bilin_pack(u00.w, u01.w, u10.w, u11.w, C00, C01, C10, C11);
      short8 a = *(short8*)&ap;
      const ushort* fbase = wdts + (size_t)((t * 2 + half) * 4) * 512 + l * 8;
#pragma unroll
      for (int j = 0; j < 4; ++j) {
        short8 bf = *(const short8*)(fbase + j * 512);
        acc[j] = __builtin_amdgcn_mfma_f32_16x16x32_bf16(a, bf, acc[j], 0, 0, 0);
      }
    }
  }

  // K-split reduction across the 4 waves. D map: col=lm(co), row=lk*4+r(pixel).
#pragma unroll
  for (int j = 0; j < 4; ++j)
#pragma unroll
    for (int r = 0; r < 4; ++r)
      s_red[w][lk * 4 + r][j * 16 + lm] = acc[j][r];
  __syncthreads();
  int rem0 = m0 - b * HW;
#pragma unroll
  for (int i = 0; i < 4; ++i) {
    int idx = i * 256 + tid;
    int mrow = idx & 15, co = idx >> 4;
    float v = s_red[0][mrow][co] + s_red[1][mrow][co] +
              s_red[2][mrow][co] + s_red[3][mrow][co];
    out[(size_t)(b * (3 * COUT) + br_off + co) * HW + rem0 + mrow] = v;
  }
}

__global__ __launch_bounds__(256, 4) void dcn_all(
    const ushort* __restrict__ xhb,
    const float* __restrict__ co7, const ushort* __restrict__ wdts7,
    const float* __restrict__ co5, const ushort* __restrict__ wdts5,
    const float* __restrict__ co3, const ushort* __restrict__ wdts3,
    float* __restrict__ out) {
  __shared__ float s_cv[16 * 147];
  __shared__ float s_red[4][16][65];
  int blk = blockIdx.x;
  if (blk < 800) dcn_body<7>(blk, xhb, co7, wdts7, out, 128, s_cv, s_red);
  else if (blk < 1600) dcn_body<5>(blk - 800, xhb, co5, wdts5, out, 64, s_cv, s_red);
  else dcn_body<3>(blk - 1600, xhb, co3, wdts3, out, 0, s_cv, s_red);
}

// ---------------------------------------------------------------------------
// Launch
// ---------------------------------------------------------------------------
extern "C" void kernel_launch(void* const* d_in, const int* in_sizes, int n_in,
                              void* d_out, int out_size, void* d_ws,
                              size_t ws_size, hipStream_t stream) {
  const float* x = (const float*)d_in[0];
  const float* w_off3 = (const float*)d_in[1];
  const float* b_off3 = (const float*)d_in[2];
  const float* w_mask3 = (const float*)d_in[3];
  const float* b_mask3 = (const float*)d_in[4];
  const float* w_dcn3 = (const float*)d_in[5];
  const float* w_off5 = (const float*)d_in[6];
  const float* b_off5 = (const float*)d_in[7];
  const float* w_mask5 = (const float*)d_in[8];
  const float* b_mask5 = (const float*)d_in[9];
  const float* w_dcn5 = (const float*)d_in[10];
  const float* w_off7 = (const float*)d_in[11];
  const float* b_off7 = (const float*)d_in[12];
  const float* w_mask7 = (const float*)d_in[13];
  const float* b_mask7 = (const float*)d_in[14];
  const float* w_dcn7 = (const float*)d_in[15];
  float* out = (float*)d_out;
  float* ws = (float*)d_ws;

  // Workspace layout (float units, 16B aligned)
  size_t off = 0;
  auto alloc = [&](size_t n) {
    size_t p = off;
    off += (n + 3) & ~(size_t)3;
    return ws + p;
  };
  ushort* xhb = (ushort*)alloc((size_t)B * HW * C / 2);  // bf16 NHWC
  float* co3 = alloc((size_t)B * HW * 27);
  float* co5 = alloc((size_t)B * HW * 75);
  float* co7 = alloc((size_t)B * HW * 147);
  ushort* wtbs3 = (ushort*)alloc(9 * 2 * 2 * 512 / 2);
  ushort* wtbs5 = (ushort*)alloc(25 * 2 * 5 * 512 / 2);
  ushort* wtbs7 = (ushort*)alloc(49 * 2 * 10 * 512 / 2);
  float* bc3 = alloc(27);
  float* bc5 = alloc(75);
  float* bc7 = alloc(147);
  ushort* wdts3 = (ushort*)alloc(9 * 2 * 4 * 512 / 2);
  ushort* wdts5 = (ushort*)alloc(25 * 2 * 4 * 512 / 2);
  ushort* wdts7 = (ushort*)alloc(49 * 2 * 4 * 512 / 2);

  // 1) transpose + all weight prep (one launch)
  setup_all<<<456, 256, 0, stream>>>(
      x, xhb,
      w_off3, b_off3, w_mask3, b_mask3, w_dcn3, wtbs3, bc3, wdts3,
      w_off5, b_off5, w_mask5, b_mask5, w_dcn5, wtbs5, bc5, wdts5,
      w_off7, b_off7, w_mask7, b_mask7, w_dcn7, wtbs7, bc7, wdts7);

  // 2) all offset+mask convs (one launch, k=7 blocks first)
  conv_all<<<1800, 256, 0, stream>>>(xhb, wtbs7, bc7, co7, wtbs5, bc5, co5,
                                     wtbs3, bc3, co3);

  // 3) all fused deformable sampling + einsum (one launch, k=7 first)
  dcn_all<<<2400, 256, 0, stream>>>(xhb, co7, wdts7, co5, wdts5, co3, wdts3,
                                    out);
}

// Round 6
// 259.715 us; speedup vs baseline: 8.3358x; 1.0202x over previous
//
#include <hip/hip_runtime.h>
#include <math.h>

constexpr int B = 2, C = 64, H = 80, W = 80, HW = H * W, COUT = 64;

typedef __attribute__((ext_vector_type(8))) short short8;   // 8 bf16
typedef __attribute__((ext_vector_type(4))) float f32x4;
typedef __attribute__((ext_vector_type(2))) float f32x2;

__device__ inline ushort f2bf(float f) {
  unsigned u = __float_as_uint(f);
  unsigned r = u + 0x7fff + ((u >> 16) & 1);   // RNE
  return (ushort)(r >> 16);
}

__device__ inline f32x2 unpack_bf2(unsigned u) {
  f32x2 r;
  r.x = __uint_as_float(u << 16);
  r.y = __uint_as_float(u & 0xffff0000u);
  return r;
}

// bilinear-combine 2 bf16 channels x 4 corners, repack to 2 bf16 (1 v_perm)
__device__ inline unsigned bilin_pack(unsigned a, unsigned b, unsigned c,
                                      unsigned d, f32x2 c00, f32x2 c01,
                                      f32x2 c10, f32x2 c11) {
  f32x2 p = unpack_bf2(a) * c00;
  p += unpack_bf2(b) * c01;
  p += unpack_bf2(c) * c10;
  p += unpack_bf2(d) * c11;
  unsigned lo = __float_as_uint(p.x) + 0x8000u;
  unsigned hi = __float_as_uint(p.y) + 0x8000u;
  return __builtin_amdgcn_perm(hi, lo, 0x07060302);
}

// ---------------------------------------------------------------------------
// Weight prep body (grid-stride over this branch's swizzled tables).
//  wtbs[((t*2+half)*NT + nt)*512 + l*8 + e]  conv B fragments (lane-ordered)
//  wdts[((t*2+half)*4 + jt)*512 + l*8 + e]   dcn  B fragments
//  bcomb[co] fp32 combined bias
// ---------------------------------------------------------------------------
template <int K, int NT>
__device__ void prep_body(int pb, int nblk, const float* __restrict__ w_off,
                          const float* __restrict__ b_off,
                          const float* __restrict__ w_mask,
                          const float* __restrict__ b_mask,
                          const float* __restrict__ w_dcn,
                          ushort* __restrict__ wtbs, float* __restrict__ bcomb,
                          ushort* __restrict__ wdts) {
  constexpr int KK = K * K, C3 = 3 * KK;
  const int n1 = KK * 2 * NT * 512;
  const int n2 = C3;
  const int n3 = KK * 2 * 4 * 512;
  const int total = n1 + n2 + n3;
  for (int i = pb * 256 + threadIdx.x; i < total; i += nblk * 256) {
    if (i < n1) {
      int e = i & 7, l = (i >> 3) & 63;
      int blk512 = i >> 9;
      int nt = blk512 % NT, th = blk512 / NT;
      int half = th & 1, t = th >> 1;
      int n = nt * 16 + (l & 15);
      int ci = half * 32 + (l >> 4) * 8 + e;
      float v = 0.f;
      if (n < 2 * KK) v = w_off[(n * C + ci) * KK + t];
      else if (n < C3) v = w_mask[((n - 2 * KK) * C + ci) * KK + t];
      wtbs[i] = f2bf(v);
    } else if (i < n1 + n2) {
      int co = i - n1;
      bcomb[co] = (co < 2 * KK) ? b_off[co] : b_mask[co - 2 * KK];
    } else {
      int j = i - n1 - n2;
      int e = j & 7, l = (j >> 3) & 63;
      int blk512 = j >> 9;
      int jt = blk512 & 3, th = blk512 >> 2;
      int half = th & 1, t = th >> 1;
      int co = jt * 16 + (l & 15);
      int ci = half * 32 + (l >> 4) * 8 + e;
      wdts[j] = f2bf(w_dcn[(co * C + ci) * KK + t]);
    }
  }
}

// ---------------------------------------------------------------------------
// setup_all: blocks 0..199 transpose NCHW->NHWC bf16; blocks 200..455 prep.
// ---------------------------------------------------------------------------
__global__ __launch_bounds__(256) void setup_all(
    const float* __restrict__ x, ushort* __restrict__ xhb,
    const float* __restrict__ w_off3, const float* __restrict__ b_off3,
    const float* __restrict__ w_mask3, const float* __restrict__ b_mask3,
    const float* __restrict__ w_dcn3, ushort* __restrict__ wtbs3,
    float* __restrict__ bc3, ushort* __restrict__ wdts3,
    const float* __restrict__ w_off5, const float* __restrict__ b_off5,
    const float* __restrict__ w_mask5, const float* __restrict__ b_mask5,
    const float* __restrict__ w_dcn5, ushort* __restrict__ wtbs5,
    float* __restrict__ bc5, ushort* __restrict__ wdts5,
    const float* __restrict__ w_off7, const float* __restrict__ b_off7,
    const float* __restrict__ w_mask7, const float* __restrict__ b_mask7,
    const float* __restrict__ w_dcn7, ushort* __restrict__ wtbs7,
    float* __restrict__ bc7, ushort* __restrict__ wdts7) {
  __shared__ float tile[64][65];
  int blk = blockIdx.x;
  if (blk < 200) {
    int b = blk / (HW / 64);
    int p0 = (blk % (HW / 64)) * 64;
    int lane = threadIdx.x & 63, row = threadIdx.x >> 6;
#pragma unroll
    for (int it = 0; it < 16; ++it) {
      int ci = it * 4 + row;
      tile[ci][lane] = x[(size_t)(b * C + ci) * HW + p0 + lane];
    }
    __syncthreads();
#pragma unroll
    for (int it = 0; it < 16; ++it) {
      int pl = it * 4 + row;
      xhb[((size_t)b * HW + p0 + pl) * C + lane] = f2bf(tile[lane][pl]);
    }
  } else {
    int pb = blk - 200;
    prep_body<7, 10>(pb, 256, w_off7, b_off7, w_mask7, b_mask7, w_dcn7, wtbs7,
                     bc7, wdts7);
    prep_body<5, 6>(pb, 256, w_off5, b_off5, w_mask5, b_mask5, w_dcn5, wtbs5,
                    bc5, wdts5);
    prep_body<3, 2>(pb, 256, w_off3, b_off3, w_mask3, b_mask3, w_dcn3, wtbs3,
                    bc3, wdts3);
  }
}

// ---------------------------------------------------------------------------
// Conv body: implicit-im2col bf16 MFMA GEMM. MB m-tiles x NTA n-tiles per
// wave, compile-time-exact tiling (no runtime guards), fully unrolled K-loop.
// ---------------------------------------------------------------------------
template <int K, int NT, int NTA, int MB>
__device__ __forceinline__ void conv_body(int blk,
                                          const ushort* __restrict__ xhb,
                                          const ushort* __restrict__ wtbs,
                                          const float* __restrict__ bcomb,
                                          float* __restrict__ convout) {
  constexpr int PAD = K / 2, KK = K * K, C3 = 3 * KK;
  constexpr int NG = NT / NTA;
  static_assert(NG * NTA == NT, "exact n-split");
  int tid = threadIdx.x;
  int wid = blk * 4 + (tid >> 6);
  int mt = wid / NG;                       // supertile of MB*16 pixels
  int g = wid % NG;
  int j0 = g * NTA;
  int l = tid & 63;
  int lm = l & 15, lk = l >> 4;
  int m0 = mt * (16 * MB);
  int b = m0 / HW;                         // (16*MB) | HW -> uniform
  const ushort* xbase = xhb + (size_t)b * HW * C;
  int y[MB], x0[MB];
#pragma unroll
  for (int i = 0; i < MB; ++i) {
    int rem = (m0 + 16 * i) % HW;
    y[i] = rem / W;
    x0[i] = rem % W;                       // 16 | W -> tile stays in one row
  }
  f32x4 acc[MB][NTA];
#pragma unroll
  for (int i = 0; i < MB; ++i)
#pragma unroll
    for (int j = 0; j < NTA; ++j) acc[i][j] = f32x4{0.f, 0.f, 0.f, 0.f};

  const short8 zero8 = {0, 0, 0, 0, 0, 0, 0, 0};
#pragma unroll
  for (int ky = 0; ky < K; ++ky) {
#pragma unroll
    for (int kx = 0; kx < K; ++kx) {
      int t = ky * K + kx;
      const ushort* fbase = wtbs + (size_t)(t * 2) * NT * 512 + l * 8;
      short8 a0[MB], a1[MB];
#pragma unroll
      for (int i = 0; i < MB; ++i) {
        int yy = y[i] + ky - PAD;
        bool vy = (unsigned)yy < (unsigned)H;
        int xx = x0[i] + lm + kx - PAD;
        bool v = vy && ((unsigned)xx < (unsigned)W);
        const ushort* ap =
            xbase + (size_t)((vy ? yy : 0) * W + (v ? xx : 0)) * C + lk * 8;
        a0[i] = *(const short8*)ap;
        a1[i] = *(const short8*)(ap + 32);
        if (!v) { a0[i] = zero8; a1[i] = zero8; }
      }
      short8 b0[NTA], b1[NTA];
#pragma unroll
      for (int jj = 0; jj < NTA; ++jj) {
        b0[jj] = *(const short8*)(fbase + (size_t)(j0 + jj) * 512);
        b1[jj] = *(const short8*)(fbase + (size_t)(NT + j0 + jj) * 512);
      }
#pragma unroll
      for (int jj = 0; jj < NTA; ++jj)
#pragma unroll
        for (int i = 0; i < MB; ++i)
          acc[i][jj] = __builtin_amdgcn_mfma_f32_16x16x32_bf16(a0[i], b0[jj],
                                                              acc[i][jj], 0, 0, 0);
#pragma unroll
      for (int jj = 0; jj < NTA; ++jj)
#pragma unroll
        for (int i = 0; i < MB; ++i)
          acc[i][jj] = __builtin_amdgcn_mfma_f32_16x16x32_bf16(a1[i], b1[jj],
                                                              acc[i][jj], 0, 0, 0);
    }
  }

  // Epilogue. D mapping: col(n)=lm, row(m)=lk*4+r.
#pragma unroll
  for (int i = 0; i < MB; ++i) {
#pragma unroll
    for (int jj = 0; jj < NTA; ++jj) {
      int co = (j0 + jj) * 16 + lm;
      if (co >= C3) continue;              // only k=5 padding hits this
      float bs = bcomb[co];
      bool isoff = co < 2 * KK;
      int tp = co >> 1;
#pragma unroll
      for (int r = 0; r < 4; ++r) {
        int xr = x0[i] + lk * 4 + r;
        int pix = m0 + 16 * i + lk * 4 + r;
        float v = acc[i][jj][r] + bs;
        if (isoff) {
          v += (co & 1) ? (float)(xr - PAD + tp % K)    // px
                        : (float)(y[i] - PAD + tp / K); // py
        } else {
          v = 1.f / (1.f + expf(-v));
        }
        convout[(size_t)pix * C3 + co] = v;
      }
    }
  }
}

__global__ __launch_bounds__(256, 4) void conv_all(
    const ushort* __restrict__ xhb,
    const ushort* __restrict__ wtbs7, const float* __restrict__ bc7, float* __restrict__ co7,
    const ushort* __restrict__ wtbs5, const float* __restrict__ bc5, float* __restrict__ co5,
    const ushort* __restrict__ wtbs3, const float* __restrict__ bc3, float* __restrict__ co3) {
  int blk = blockIdx.x;
  if (blk < 500) conv_body<7, 10, 2, 2>(blk, xhb, wtbs7, bc7, co7);        // NG=5
  else if (blk < 700) conv_body<5, 6, 3, 2>(blk - 500, xhb, wtbs5, bc5, co5); // NG=2
  else conv_body<3, 2, 2, 2>(blk - 700, xhb, wtbs3, bc3, co3);             // NG=1
}

// ---------------------------------------------------------------------------
// DCN body: fused deformable-sampling + einsum as implicit-A bf16 MFMA GEMM.
// Block = 16 pixels; 4 waves split KK taps (padded to 4*TPW, dummy taps have
// zero coefficients); uniform fully-unrolled tap loop; LDS K-split reduction.
// ---------------------------------------------------------------------------
template <int K>
__device__ __forceinline__ void dcn_body(int blk, const ushort* __restrict__ xhb,
                                         const float* __restrict__ convout,
                                         const ushort* __restrict__ wdts,
                                         float* __restrict__ out, int br_off,
                                         float* s_cv, float (*s_red)[16][65]) {
  constexpr int KK = K * K, C3 = 3 * KK;
  constexpr int TPW = (KK + 3) / 4;
  int tid = threadIdx.x, w = tid >> 6, l = tid & 63;
  int lm = l & 15, lk = l >> 4;
  int m0 = blk * 16;
  int b = m0 / HW;
  const ushort* xb = xhb + (size_t)b * HW * C;
  for (int idx = tid; idx < 16 * C3; idx += 256)
    s_cv[idx] = convout[(size_t)m0 * C3 + idx];
  __syncthreads();
  const float* cp = s_cv + lm * C3;
  f32x4 acc[4];
#pragma unroll
  for (int j = 0; j < 4; ++j) acc[j] = f32x4{0.f, 0.f, 0.f, 0.f};

#pragma unroll
  for (int tt = 0; tt < TPW; ++tt) {
    int t = w * TPW + tt;                  // wave-uniform, may exceed KK
    bool tv = t < KK;
    int ts = tv ? t : 0;
    float py = cp[2 * ts], px = cp[2 * ts + 1];
    float m = tv ? cp[2 * KK + ts] : 0.f;  // dummy taps contribute exactly 0
    float fy = floorf(py), fx = floorf(px);
    float wy1 = py - fy, wx1 = px - fx;
    float wy0 = 1.f - wy1, wx0 = 1.f - wx1;
    int y0 = (int)fy, x0 = (int)fx;
    int y1 = y0 + 1, x1 = x0 + 1;
    bool vy0 = (unsigned)y0 < (unsigned)H, vy1 = (unsigned)y1 < (unsigned)H;
    bool vx0 = (unsigned)x0 < (unsigned)W, vx1 = (unsigned)x1 < (unsigned)W;
    float c00 = m * wy0 * wx0 * ((vy0 & vx0) ? 1.f : 0.f);
    float c01 = m * wy0 * wx1 * ((vy0 & vx1) ? 1.f : 0.f);
    float c10 = m * wy1 * wx0 * ((vy1 & vx0) ? 1.f : 0.f);
    float c11 = m * wy1 * wx1 * ((vy1 & vx1) ? 1.f : 0.f);
    f32x2 C00 = {c00, c00}, C01 = {c01, c01}, C10 = {c10, c10}, C11 = {c11, c11};
    int y0c = min(max(y0, 0), H - 1), y1c = min(max(y1, 0), H - 1);
    int x0c = min(max(x0, 0), W - 1), x1c = min(max(x1, 0), W - 1);
    int i00 = (y0c * W + x0c) * C + lk * 8, i01 = (y0c * W + x1c) * C + lk * 8;
    int i10 = (y1c * W + x0c) * C + lk * 8, i11 = (y1c * W + x1c) * C + lk * 8;
    // issue all 8 corner loads (both halves) before any packing
    uint4 u00a = *(const uint4*)(xb + i00),      u00b = *(const uint4*)(xb + i00 + 32);
    uint4 u01a = *(const uint4*)(xb + i01),      u01b = *(const uint4*)(xb + i01 + 32);
    uint4 u10a = *(const uint4*)(xb + i10),      u10b = *(const uint4*)(xb + i10 + 32);
    uint4 u11a = *(const uint4*)(xb + i11),      u11b = *(const uint4*)(xb + i11 + 32);
    const ushort* fb0 = wdts + (size_t)((ts * 2 + 0) * 4) * 512 + l * 8;
    const ushort* fb1 = wdts + (size_t)((ts * 2 + 1) * 4) * 512 + l * 8;
    uint4 apa, apb;
    apa.x = bilin_pack(u00a.x, u01a.x, u10a.x, u11a.x, C00, C01, C10, C11);
    apa.y = bilin_pack(u00a.y, u01a.y, u10a.y, u11a.y, C00, C01, C10, C11);
    apa.z = bilin_pack(u00a.z, u01a.z, u10a.z, u11a.z, C00, C01, C10, C11);
    apa.w = bilin_pack(u00a.w, u01a.w, u10a.w, u11a.w, C00, C01, C10, C11);
    apb.x = bilin_pack(u00b.x, u01b.x, u10b.x, u11b.x, C00, C01, C10, C11);
    apb.y = bilin_pack(u00b.y, u01b.y, u10b.y, u11b.y, C00, C01, C10, C11);
    apb.z = bilin_pack(u00b.z, u01b.z, u10b.z, u11b.z, C00, C01, C10, C11);
    apb.w = bilin_pack(u00b.w, u01b.w, u10b.w, u11b.w, C00, C01, C10, C11);
    short8 aa = *(short8*)&apa;
    short8 ab = *(short8*)&apb;
#pragma unroll
    for (int j = 0; j < 4; ++j) {
      short8 bf = *(const short8*)(fb0 + j * 512);
      acc[j] = __builtin_amdgcn_mfma_f32_16x16x32_bf16(aa, bf, acc[j], 0, 0, 0);
    }
#pragma unroll
    for (int j = 0; j < 4; ++j) {
      short8 bf = *(const short8*)(fb1 + j * 512);
      acc[j] = __builtin_amdgcn_mfma_f32_16x16x32_bf16(ab, bf, acc[j], 0, 0, 0);
    }
  }

  // K-split reduction across the 4 waves. D map: col=lm(co), row=lk*4+r(pixel).
#pragma unroll
  for (int j = 0; j < 4; ++j)
#pragma unroll
    for (int r = 0; r < 4; ++r)
      s_red[w][lk * 4 + r][j * 16 + lm] = acc[j][r];
  __syncthreads();
  int rem0 = m0 - b * HW;
#pragma unroll
  for (int i = 0; i < 4; ++i) {
    int idx = i * 256 + tid;
    int mrow = idx & 15, co = idx >> 4;
    float v = s_red[0][mrow][co] + s_red[1][mrow][co] +
              s_red[2][mrow][co] + s_red[3][mrow][co];
    out[(size_t)(b * (3 * COUT) + br_off + co) * HW + rem0 + mrow] = v;
  }
}

__global__ __launch_bounds__(256, 4) void dcn_all(
    const ushort* __restrict__ xhb,
    const float* __restrict__ co7, const ushort* __restrict__ wdts7,
    const float* __restrict__ co5, const ushort* __restrict__ wdts5,
    const float* __restrict__ co3, const ushort* __restrict__ wdts3,
    float* __restrict__ out) {
  __shared__ float s_cv[16 * 147];
  __shared__ float s_red[4][16][65];
  int blk = blockIdx.x;
  if (blk < 800) dcn_body<7>(blk, xhb, co7, wdts7, out, 128, s_cv, s_red);
  else if (blk < 1600) dcn_body<5>(blk - 800, xhb, co5, wdts5, out, 64, s_cv, s_red);
  else dcn_body<3>(blk - 1600, xhb, co3, wdts3, out, 0, s_cv, s_red);
}

// ---------------------------------------------------------------------------
// Launch
// ---------------------------------------------------------------------------
extern "C" void kernel_launch(void* const* d_in, const int* in_sizes, int n_in,
                              void* d_out, int out_size, void* d_ws,
                              size_t ws_size, hipStream_t stream) {
  const float* x = (const float*)d_in[0];
  const float* w_off3 = (const float*)d_in[1];
  const float* b_off3 = (const float*)d_in[2];
  const float* w_mask3 = (const float*)d_in[3];
  const float* b_mask3 = (const float*)d_in[4];
  const float* w_dcn3 = (const float*)d_in[5];
  const float* w_off5 = (const float*)d_in[6];
  const float* b_off5 = (const float*)d_in[7];
  const float* w_mask5 = (const float*)d_in[8];
  const float* b_mask5 = (const float*)d_in[9];
  const float* w_dcn5 = (const float*)d_in[10];
  const float* w_off7 = (const float*)d_in[11];
  const float* b_off7 = (const float*)d_in[12];
  const float* w_mask7 = (const float*)d_in[13];
  const float* b_mask7 = (const float*)d_in[14];
  const float* w_dcn7 = (const float*)d_in[15];
  float* out = (float*)d_out;
  float* ws = (float*)d_ws;

  // Workspace layout (float units, 16B aligned)
  size_t off = 0;
  auto alloc = [&](size_t n) {
    size_t p = off;
    off += (n + 3) & ~(size_t)3;
    return ws + p;
  };
  ushort* xhb = (ushort*)alloc((size_t)B * HW * C / 2);  // bf16 NHWC
  float* co3 = alloc((size_t)B * HW * 27);
  float* co5 = alloc((size_t)B * HW * 75);
  float* co7 = alloc((size_t)B * HW * 147);
  ushort* wtbs3 = (ushort*)alloc(9 * 2 * 2 * 512 / 2);
  ushort* wtbs5 = (ushort*)alloc(25 * 2 * 6 * 512 / 2);
  ushort* wtbs7 = (ushort*)alloc(49 * 2 * 10 * 512 / 2);
  float* bc3 = alloc(27);
  float* bc5 = alloc(75);
  float* bc7 = alloc(147);
  ushort* wdts3 = (ushort*)alloc(9 * 2 * 4 * 512 / 2);
  ushort* wdts5 = (ushort*)alloc(25 * 2 * 4 * 512 / 2);
  ushort* wdts7 = (ushort*)alloc(49 * 2 * 4 * 512 / 2);

  // 1) transpose + all weight prep (one launch)
  setup_all<<<456, 256, 0, stream>>>(
      x, xhb,
      w_off3, b_off3, w_mask3, b_mask3, w_dcn3, wtbs3, bc3, wdts3,
      w_off5, b_off5, w_mask5, b_mask5, w_dcn5, wtbs5, bc5, wdts5,
      w_off7, b_off7, w_mask7, b_mask7, w_dcn7, wtbs7, bc7, wdts7);

  // 2) all offset+mask convs (one launch; k=7 500 blocks, k=5 200, k=3 100)
  conv_all<<<800, 256, 0, stream>>>(xhb, wtbs7, bc7, co7, wtbs5, bc5, co5,
                                    wtbs3, bc3, co3);

  // 3) all fused deformable sampling + einsum (one launch, k=7 first)
  dcn_all<<<2400, 256, 0, stream>>>(xhb, co7, wdts7, co5, wdts5, co3, wdts3,
                                    out);
}

// Round 7
// 255.426 us; speedup vs baseline: 8.4758x; 1.0168x over previous
//
#include <hip/hip_runtime.h>
#include <math.h>

constexpr int B = 2, C = 64, H = 80, W = 80, HW = H * W, COUT = 64;

typedef __attribute__((ext_vector_type(8))) short short8;   // 8 bf16
typedef __attribute__((ext_vector_type(4))) float f32x4;
typedef __attribute__((ext_vector_type(2))) float f32x2;

__device__ inline ushort f2bf(float f) {
  unsigned u = __float_as_uint(f);
  unsigned r = u + 0x7fff + ((u >> 16) & 1);   // RNE
  return (ushort)(r >> 16);
}

__device__ inline f32x2 unpack_bf2(unsigned u) {
  f32x2 r;
  r.x = __uint_as_float(u << 16);
  r.y = __uint_as_float(u & 0xffff0000u);
  return r;
}

// bilinear-combine 2 bf16 channels x 4 corners, repack to 2 bf16 (1 v_perm)
__device__ inline unsigned bilin_pack(unsigned a, unsigned b, unsigned c,
                                      unsigned d, f32x2 c00, f32x2 c01,
                                      f32x2 c10, f32x2 c11) {
  f32x2 p = unpack_bf2(a) * c00;
  p += unpack_bf2(b) * c01;
  p += unpack_bf2(c) * c10;
  p += unpack_bf2(d) * c11;
  unsigned lo = __float_as_uint(p.x) + 0x8000u;
  unsigned hi = __float_as_uint(p.y) + 0x8000u;
  return __builtin_amdgcn_perm(hi, lo, 0x07060302);
}

// ---------------------------------------------------------------------------
// Weight prep body (grid-stride over this branch's swizzled tables).
// ---------------------------------------------------------------------------
template <int K, int NT>
__device__ void prep_body(int pb, int nblk, const float* __restrict__ w_off,
                          const float* __restrict__ b_off,
                          const float* __restrict__ w_mask,
                          const float* __restrict__ b_mask,
                          const float* __restrict__ w_dcn,
                          ushort* __restrict__ wtbs, float* __restrict__ bcomb,
                          ushort* __restrict__ wdts) {
  constexpr int KK = K * K, C3 = 3 * KK;
  const int n1 = KK * 2 * NT * 512;
  const int n2 = C3;
  const int n3 = KK * 2 * 4 * 512;
  const int total = n1 + n2 + n3;
  for (int i = pb * 256 + threadIdx.x; i < total; i += nblk * 256) {
    if (i < n1) {
      int e = i & 7, l = (i >> 3) & 63;
      int blk512 = i >> 9;
      int nt = blk512 % NT, th = blk512 / NT;
      int half = th & 1, t = th >> 1;
      int n = nt * 16 + (l & 15);
      int ci = half * 32 + (l >> 4) * 8 + e;
      float v = 0.f;
      if (n < 2 * KK) v = w_off[(n * C + ci) * KK + t];
      else if (n < C3) v = w_mask[((n - 2 * KK) * C + ci) * KK + t];
      wtbs[i] = f2bf(v);
    } else if (i < n1 + n2) {
      int co = i - n1;
      bcomb[co] = (co < 2 * KK) ? b_off[co] : b_mask[co - 2 * KK];
    } else {
      int j = i - n1 - n2;
      int e = j & 7, l = (j >> 3) & 63;
      int blk512 = j >> 9;
      int jt = blk512 & 3, th = blk512 >> 2;
      int half = th & 1, t = th >> 1;
      int co = jt * 16 + (l & 15);
      int ci = half * 32 + (l >> 4) * 8 + e;
      wdts[j] = f2bf(w_dcn[(co * C + ci) * KK + t]);
    }
  }
}

// ---------------------------------------------------------------------------
// setup_all: blocks 0..199 transpose NCHW->NHWC bf16 (+zero row); rest prep.
// ---------------------------------------------------------------------------
__global__ __launch_bounds__(256) void setup_all(
    const float* __restrict__ x, ushort* __restrict__ xhb,
    const float* __restrict__ w_off3, const float* __restrict__ b_off3,
    const float* __restrict__ w_mask3, const float* __restrict__ b_mask3,
    const float* __restrict__ w_dcn3, ushort* __restrict__ wtbs3,
    float* __restrict__ bc3, ushort* __restrict__ wdts3,
    const float* __restrict__ w_off5, const float* __restrict__ b_off5,
    const float* __restrict__ w_mask5, const float* __restrict__ b_mask5,
    const float* __restrict__ w_dcn5, ushort* __restrict__ wtbs5,
    float* __restrict__ bc5, ushort* __restrict__ wdts5,
    const float* __restrict__ w_off7, const float* __restrict__ b_off7,
    const float* __restrict__ w_mask7, const float* __restrict__ b_mask7,
    const float* __restrict__ w_dcn7, ushort* __restrict__ wtbs7,
    float* __restrict__ bc7, ushort* __restrict__ wdts7) {
  __shared__ float tile[64][65];
  int blk = blockIdx.x;
  if (blk < 200) {
    int b = blk / (HW / 64);
    int p0 = (blk % (HW / 64)) * 64;
    int lane = threadIdx.x & 63, row = threadIdx.x >> 6;
    if (blk == 0 && threadIdx.x < 64)
      xhb[(size_t)B * HW * C + threadIdx.x] = 0;   // zero row for OOB loads
#pragma unroll
    for (int it = 0; it < 16; ++it) {
      int ci = it * 4 + row;
      tile[ci][lane] = x[(size_t)(b * C + ci) * HW + p0 + lane];
    }
    __syncthreads();
#pragma unroll
    for (int it = 0; it < 16; ++it) {
      int pl = it * 4 + row;
      xhb[((size_t)b * HW + p0 + pl) * C + lane] = f2bf(tile[lane][pl]);
    }
  } else {
    int pb = blk - 200;
    prep_body<7, 10>(pb, 256, w_off7, b_off7, w_mask7, b_mask7, w_dcn7, wtbs7,
                     bc7, wdts7);
    prep_body<5, 6>(pb, 256, w_off5, b_off5, w_mask5, b_mask5, w_dcn5, wtbs5,
                    bc5, wdts5);
    prep_body<3, 2>(pb, 256, w_off3, b_off3, w_mask3, b_mask3, w_dcn3, wtbs3,
                    bc3, wdts3);
  }
}

// ---------------------------------------------------------------------------
// Conv body: implicit-im2col bf16 MFMA GEMM, 2-stage software pipeline,
// OOB handled by zero-row redirect (no data-dependent cndmask).
// ---------------------------------------------------------------------------
template <int K, int NT, int NTA, int MB>
__device__ __forceinline__ void conv_body(int blk,
                                          const ushort* __restrict__ xhb,
                                          const ushort* __restrict__ wtbs,
                                          const float* __restrict__ bcomb,
                                          float* __restrict__ convout) {
  constexpr int PAD = K / 2, KK = K * K, C3 = 3 * KK;
  constexpr int NG = NT / NTA;
  static_assert(NG * NTA == NT, "exact n-split");
  const int ZPIX = B * HW;                 // zero-row pixel index
  int tid = threadIdx.x;
  int wid = blk * 4 + (tid >> 6);
  int mt = wid / NG;
  int g = wid % NG;
  int j0 = g * NTA;
  int l = tid & 63;
  int lm = l & 15, lk = l >> 4;
  int m0 = mt * (16 * MB);
  int b = m0 / HW;
  int y[MB], x0[MB];
#pragma unroll
  for (int i = 0; i < MB; ++i) {
    int rem = (m0 + 16 * i) % HW;
    y[i] = rem / W;
    x0[i] = rem % W;                       // 16 | W -> tile stays in one row
  }
  f32x4 acc[MB][NTA];
#pragma unroll
  for (int i = 0; i < MB; ++i)
#pragma unroll
    for (int j = 0; j < NTA; ++j) acc[i][j] = f32x4{0.f, 0.f, 0.f, 0.f};

  short8 A0[2][MB], A1[2][MB], Bf0[2][NTA], Bf1[2][NTA];

  auto load_tap = [&](int t, int s) {
    int ky = t / K, kx = t % K;
#pragma unroll
    for (int i = 0; i < MB; ++i) {
      int yy = y[i] + ky - PAD;
      int xx = x0[i] + lm + kx - PAD;
      bool v = ((unsigned)yy < (unsigned)H) && ((unsigned)xx < (unsigned)W);
      int pidx = b * HW + yy * W + xx;
      const ushort* ap = xhb + (size_t)(v ? pidx : ZPIX) * C + lk * 8;
      A0[s][i] = *(const short8*)ap;
      A1[s][i] = *(const short8*)(ap + 32);
    }
    const ushort* fbase = wtbs + (size_t)(t * 2) * NT * 512 + l * 8;
#pragma unroll
    for (int jj = 0; jj < NTA; ++jj) {
      Bf0[s][jj] = *(const short8*)(fbase + (size_t)(j0 + jj) * 512);
      Bf1[s][jj] = *(const short8*)(fbase + (size_t)(NT + j0 + jj) * 512);
    }
  };

  load_tap(0, 0);
#pragma unroll
  for (int t = 0; t < KK; ++t) {
    int s = t & 1;
    if (t + 1 < KK) load_tap(t + 1, s ^ 1);
#pragma unroll
    for (int jj = 0; jj < NTA; ++jj)
#pragma unroll
      for (int i = 0; i < MB; ++i)
        acc[i][jj] = __builtin_amdgcn_mfma_f32_16x16x32_bf16(A0[s][i], Bf0[s][jj],
                                                            acc[i][jj], 0, 0, 0);
#pragma unroll
    for (int jj = 0; jj < NTA; ++jj)
#pragma unroll
      for (int i = 0; i < MB; ++i)
        acc[i][jj] = __builtin_amdgcn_mfma_f32_16x16x32_bf16(A1[s][i], Bf1[s][jj],
                                                            acc[i][jj], 0, 0, 0);
  }

  // Epilogue. D mapping: col(n)=lm, row(m)=lk*4+r.
#pragma unroll
  for (int i = 0; i < MB; ++i) {
#pragma unroll
    for (int jj = 0; jj < NTA; ++jj) {
      int co = (j0 + jj) * 16 + lm;
      if (co >= C3) continue;              // only k=5 padding hits this
      float bs = bcomb[co];
      bool isoff = co < 2 * KK;
      int tp = co >> 1;
#pragma unroll
      for (int r = 0; r < 4; ++r) {
        int xr = x0[i] + lk * 4 + r;
        int pix = m0 + 16 * i + lk * 4 + r;
        float v = acc[i][jj][r] + bs;
        if (isoff) {
          v += (co & 1) ? (float)(xr - PAD + tp % K)    // px
                        : (float)(y[i] - PAD + tp / K); // py
        } else {
          v = 1.f / (1.f + expf(-v));
        }
        convout[(size_t)pix * C3 + co] = v;
      }
    }
  }
}

__global__ __launch_bounds__(256, 3) void conv_all(
    const ushort* __restrict__ xhb,
    const ushort* __restrict__ wtbs7, const float* __restrict__ bc7, float* __restrict__ co7,
    const ushort* __restrict__ wtbs5, const float* __restrict__ bc5, float* __restrict__ co5,
    const ushort* __restrict__ wtbs3, const float* __restrict__ bc3, float* __restrict__ co3) {
  int blk = blockIdx.x;
  if (blk < 500) conv_body<7, 10, 2, 2>(blk, xhb, wtbs7, bc7, co7);           // NG=5
  else if (blk < 700) conv_body<5, 6, 3, 2>(blk - 500, xhb, wtbs5, bc5, co5); // NG=2
  else conv_body<3, 2, 2, 2>(blk - 700, xhb, wtbs3, bc3, co3);                // NG=1
}

// ---------------------------------------------------------------------------
// DCN body: fused deformable-sampling + einsum as implicit-A bf16 MFMA GEMM.
// 2-stage pipeline over taps; s_cv/s_red share LDS (sync between phases).
// ---------------------------------------------------------------------------
template <int K>
__device__ __forceinline__ void dcn_body(int blk, const ushort* __restrict__ xhb,
                                         const float* __restrict__ convout,
                                         const ushort* __restrict__ wdts,
                                         float* __restrict__ out, int br_off,
                                         float* smem) {
  constexpr int KK = K * K, C3 = 3 * KK;
  constexpr int TPW = (KK + 3) / 4;
  float* s_cv = smem;                                 // 16*C3 floats
  float (*s_red)[16][65] = (float (*)[16][65])smem;   // 4*16*65 floats (reused)
  int tid = threadIdx.x, w = tid >> 6, l = tid & 63;
  int lm = l & 15, lk = l >> 4;
  int m0 = blk * 16;
  int b = m0 / HW;
  const ushort* xb = xhb + (size_t)b * HW * C;
  for (int idx = tid; idx < 16 * C3; idx += 256)
    s_cv[idx] = convout[(size_t)m0 * C3 + idx];
  __syncthreads();
  const float* cp = s_cv + lm * C3;
  f32x4 acc[4];
#pragma unroll
  for (int j = 0; j < 4; ++j) acc[j] = f32x4{0.f, 0.f, 0.f, 0.f};

  uint4 U[2][8];
  f32x2 CC[2][4];
  int TS[2];

  auto load_tap = [&](int tt, int s) {
    int t = w * TPW + tt;                  // wave-uniform, may exceed KK
    bool tv = t < KK;
    int ts = tv ? t : 0;
    float py = cp[2 * ts], px = cp[2 * ts + 1];
    float m = tv ? cp[2 * KK + ts] : 0.f;  // dummy taps contribute exactly 0
    float fy = floorf(py), fx = floorf(px);
    float wy1 = py - fy, wx1 = px - fx;
    float wy0 = 1.f - wy1, wx0 = 1.f - wx1;
    int y0 = (int)fy, x0 = (int)fx;
    int y1 = y0 + 1, x1 = x0 + 1;
    bool vy0 = (unsigned)y0 < (unsigned)H, vy1 = (unsigned)y1 < (unsigned)H;
    bool vx0 = (unsigned)x0 < (unsigned)W, vx1 = (unsigned)x1 < (unsigned)W;
    float c00 = m * wy0 * wx0 * ((vy0 & vx0) ? 1.f : 0.f);
    float c01 = m * wy0 * wx1 * ((vy0 & vx1) ? 1.f : 0.f);
    float c10 = m * wy1 * wx0 * ((vy1 & vx0) ? 1.f : 0.f);
    float c11 = m * wy1 * wx1 * ((vy1 & vx1) ? 1.f : 0.f);
    CC[s][0] = f32x2{c00, c00};
    CC[s][1] = f32x2{c01, c01};
    CC[s][2] = f32x2{c10, c10};
    CC[s][3] = f32x2{c11, c11};
    int y0c = min(max(y0, 0), H - 1), y1c = min(max(y1, 0), H - 1);
    int x0c = min(max(x0, 0), W - 1), x1c = min(max(x1, 0), W - 1);
    int i00 = (y0c * W + x0c) * C + lk * 8, i01 = (y0c * W + x1c) * C + lk * 8;
    int i10 = (y1c * W + x0c) * C + lk * 8, i11 = (y1c * W + x1c) * C + lk * 8;
    U[s][0] = *(const uint4*)(xb + i00);
    U[s][1] = *(const uint4*)(xb + i00 + 32);
    U[s][2] = *(const uint4*)(xb + i01);
    U[s][3] = *(const uint4*)(xb + i01 + 32);
    U[s][4] = *(const uint4*)(xb + i10);
    U[s][5] = *(const uint4*)(xb + i10 + 32);
    U[s][6] = *(const uint4*)(xb + i11);
    U[s][7] = *(const uint4*)(xb + i11 + 32);
    TS[s] = ts;
  };

  load_tap(0, 0);
#pragma unroll
  for (int tt = 0; tt < TPW; ++tt) {
    int s = tt & 1;
    if (tt + 1 < TPW) load_tap(tt + 1, s ^ 1);
    f32x2 c00 = CC[s][0], c01 = CC[s][1], c10 = CC[s][2], c11 = CC[s][3];
    uint4 apa, apb;
    apa.x = bilin_pack(U[s][0].x, U[s][2].x, U[s][4].x, U[s][6].x, c00, c01, c10, c11);
    apa.y = bilin_pack(U[s][0].y, U[s][2].y, U[s][4].y, U[s][6].y, c00, c01, c10, c11);
    apa.z = bilin_pack(U[s][0].z, U[s][2].z, U[s][4].z, U[s][6].z, c00, c01, c10, c11);
    apa.w = bilin_pack(U[s][0].w, U[s][2].w, U[s][4].w, U[s][6].w, c00, c01, c10, c11);
    apb.x = bilin_pack(U[s][1].x, U[s][3].x, U[s][5].x, U[s][7].x, c00, c01, c10, c11);
    apb.y = bilin_pack(U[s][1].y, U[s][3].y, U[s][5].y, U[s][7].y, c00, c01, c10, c11);
    apb.z = bilin_pack(U[s][1].z, U[s][3].z, U[s][5].z, U[s][7].z, c00, c01, c10, c11);
    apb.w = bilin_pack(U[s][1].w, U[s][3].w, U[s][5].w, U[s][7].w, c00, c01, c10, c11);
    short8 aa = *(short8*)&apa;
    short8 ab = *(short8*)&apb;
    const ushort* fb0 = wdts + (size_t)((TS[s] * 2 + 0) * 4) * 512 + l * 8;
    const ushort* fb1 = wdts + (size_t)((TS[s] * 2 + 1) * 4) * 512 + l * 8;
#pragma unroll
    for (int j = 0; j < 4; ++j) {
      short8 bf = *(const short8*)(fb0 + j * 512);
      acc[j] = __builtin_amdgcn_mfma_f32_16x16x32_bf16(aa, bf, acc[j], 0, 0, 0);
    }
#pragma unroll
    for (int j = 0; j < 4; ++j) {
      short8 bf = *(const short8*)(fb1 + j * 512);
      acc[j] = __builtin_amdgcn_mfma_f32_16x16x32_bf16(ab, bf, acc[j], 0, 0, 0);
    }
  }

  __syncthreads();   // all s_cv reads done before s_red overwrites the union
  // K-split reduction across the 4 waves. D map: col=lm(co), row=lk*4+r(pixel).
#pragma unroll
  for (int j = 0; j < 4; ++j)
#pragma unroll
    for (int r = 0; r < 4; ++r)
      s_red[w][lk * 4 + r][j * 16 + lm] = acc[j][r];
  __syncthreads();
  int rem0 = m0 - b * HW;
#pragma unroll
  for (int i = 0; i < 4; ++i) {
    int idx = i * 256 + tid;
    int mrow = idx & 15, co = idx >> 4;
    float v = s_red[0][mrow][co] + s_red[1][mrow][co] +
              s_red[2][mrow][co] + s_red[3][mrow][co];
    out[(size_t)(b * (3 * COUT) + br_off + co) * HW + rem0 + mrow] = v;
  }
}

__global__ __launch_bounds__(256, 3) void dcn_all(
    const ushort* __restrict__ xhb,
    const float* __restrict__ co7, const ushort* __restrict__ wdts7,
    const float* __restrict__ co5, const ushort* __restrict__ wdts5,
    const float* __restrict__ co3, const ushort* __restrict__ wdts3,
    float* __restrict__ out) {
  __shared__ float smem[4 * 16 * 65];   // union: s_cv (<=2352) / s_red (4160)
  int blk = blockIdx.x;
  if (blk < 800) dcn_body<7>(blk, xhb, co7, wdts7, out, 128, smem);
  else if (blk < 1600) dcn_body<5>(blk - 800, xhb, co5, wdts5, out, 64, smem);
  else dcn_body<3>(blk - 1600, xhb, co3, wdts3, out, 0, smem);
}

// ---------------------------------------------------------------------------
// Launch
// ---------------------------------------------------------------------------
extern "C" void kernel_launch(void* const* d_in, const int* in_sizes, int n_in,
                              void* d_out, int out_size, void* d_ws,
                              size_t ws_size, hipStream_t stream) {
  const float* x = (const float*)d_in[0];
  const float* w_off3 = (const float*)d_in[1];
  const float* b_off3 = (const float*)d_in[2];
  const float* w_mask3 = (const float*)d_in[3];
  const float* b_mask3 = (const float*)d_in[4];
  const float* w_dcn3 = (const float*)d_in[5];
  const float* w_off5 = (const float*)d_in[6];
  const float* b_off5 = (const float*)d_in[7];
  const float* w_mask5 = (const float*)d_in[8];
  const float* b_mask5 = (const float*)d_in[9];
  const float* w_dcn5 = (const float*)d_in[10];
  const float* w_off7 = (const float*)d_in[11];
  const float* b_off7 = (const float*)d_in[12];
  const float* w_mask7 = (const float*)d_in[13];
  const float* b_mask7 = (const float*)d_in[14];
  const float* w_dcn7 = (const float*)d_in[15];
  float* out = (float*)d_out;
  float* ws = (float*)d_ws;

  // Workspace layout (float units, 16B aligned)
  size_t off = 0;
  auto alloc = [&](size_t n) {
    size_t p = off;
    off += (n + 3) & ~(size_t)3;
    return ws + p;
  };
  ushort* xhb = (ushort*)alloc((size_t)B * HW * C / 2 + 64);  // +zero row
  float* co3 = alloc((size_t)B * HW * 27);
  float* co5 = alloc((size_t)B * HW * 75);
  float* co7 = alloc((size_t)B * HW * 147);
  ushort* wtbs3 = (ushort*)alloc(9 * 2 * 2 * 512 / 2);
  ushort* wtbs5 = (ushort*)alloc(25 * 2 * 6 * 512 / 2);
  ushort* wtbs7 = (ushort*)alloc(49 * 2 * 10 * 512 / 2);
  float* bc3 = alloc(27);
  float* bc5 = alloc(75);
  float* bc7 = alloc(147);
  ushort* wdts3 = (ushort*)alloc(9 * 2 * 4 * 512 / 2);
  ushort* wdts5 = (ushort*)alloc(25 * 2 * 4 * 512 / 2);
  ushort* wdts7 = (ushort*)alloc(49 * 2 * 4 * 512 / 2);

  // 1) transpose + all weight prep (one launch)
  setup_all<<<456, 256, 0, stream>>>(
      x, xhb,
      w_off3, b_off3, w_mask3, b_mask3, w_dcn3, wtbs3, bc3, wdts3,
      w_off5, b_off5, w_mask5, b_mask5, w_dcn5, wtbs5, bc5, wdts5,
      w_off7, b_off7, w_mask7, b_mask7, w_dcn7, wtbs7, bc7, wdts7);

  // 2) all offset+mask convs (one launch; k=7 500 blocks, k=5 200, k=3 100)
  conv_all<<<800, 256, 0, stream>>>(xhb, wtbs7, bc7, co7, wtbs5, bc5, co5,
                                    wtbs3, bc3, co3);

  // 3) all fused deformable sampling + einsum (one launch, k=7 first)
  dcn_all<<<2400, 256, 0, stream>>>(xhb, co7, wdts7, co5, wdts5, co3, wdts3,
                                    out);
}